// Round 6
// baseline (929.360 us; speedup 1.0000x reference)
//
#include <hip/hip_runtime.h>
#include <hip/hip_bf16.h>
#include <hip/hip_fp16.h>

#define BB 256
#define SS 32
#define II 128
#define HH 256
#define LBL 200
#define NSUBS 491
#define NATOMS_N 8000
#define NMOL_N 600

typedef const float* fp;
typedef __attribute__((ext_vector_type(8))) _Float16 f16x8;
typedef __attribute__((ext_vector_type(4))) float f32x4;

__device__ __forceinline__ float sigm(float x) { return 1.f / (1.f + expf(-x)); }

// ---------------------------------------------------------------------------
// prep (1126 blocks): idxv, mstart, masked w_masklin, and SPLIT-fp16
// conversions of x and w_ih (hi + residual lo) for the xp matrix-core GEMM.
// ---------------------------------------------------------------------------
__global__ __launch_bounds__(256) void prep_kernel(
    const int* __restrict__ mask, int* __restrict__ idxv,
    const int* __restrict__ seg, int* __restrict__ mstart,
    fp w_masklin, fp ddi, float* __restrict__ mw,
    fp x_c, fp x_p, __half* __restrict__ xhi, __half* __restrict__ xlo,
    fp wih_c, fp wih_p, __half* __restrict__ whi, __half* __restrict__ wlo)
{
  int bx = blockIdx.x, tid = threadIdx.x;
  if (bx == 0) {                         // idx[b] = clamp(sum(mask[b,:]) - 1)
    int s = 0;
    const int* mrow = mask + tid * SS;
    for (int t = 0; t < SS; ++t) s += mrow[t];
    s -= 1;
    if (s < 0) s = 0;
    if (s > SS - 1) s = SS - 1;
    idxv[tid] = s;
  } else if (bx == 1) {                  // mstart[m] = lower_bound(seg, m)
    for (int m = tid; m <= NMOL_N; m += 256) {
      if (m == NMOL_N) { mstart[m] = NATOMS_N; continue; }
      int lo = 0, hi = NATOMS_N;
      while (lo < hi) {
        int mid = (lo + hi) >> 1;
        if (seg[mid] < m) lo = mid + 1; else hi = mid;
      }
      mstart[m] = lo;
    }
  } else if (bx < 6) {                   // mw[s][l] = w_masklin[s][l]*ddi[l][s]
    for (int o = (bx - 2) * 256 + tid; o < NSUBS * LBL; o += 4 * 256) {
      int s = o / LBL, l = o - s * LBL;
      mw[o] = w_masklin[o] * ddi[l * NSUBS + s];
    }
  } else if (bx < 1030) {                // x -> fp16 hi+lo (2 x 1048576)
    int base = (bx - 6) * 2048;
    for (int o = base + tid; o < base + 2048; o += 256) {
      float v = (o < 1048576) ? x_c[o] : x_p[o - 1048576];
      __half h = __float2half(v);
      xhi[o] = h;
      xlo[o] = __float2half(v - __half2float(h));
    }
  } else {                               // w_ih -> fp16 hi+lo (2 x 98304)
    int base = (bx - 1030) * 2048;
    for (int o = base + tid; o < base + 2048; o += 256) {
      float v = (o < 98304) ? wih_c[o] : wih_p[o - 98304];
      __half h = __float2half(v);
      whi[o] = h;
      wlo[o] = __float2half(v - __half2float(h));
    }
  }
}

// ---------------------------------------------------------------------------
// xp = x @ w_ih.T + b_ih via SPLIT-fp16 MFMA (3 chains: hi*whi + lo*whi +
// hi*wlo) -> fp32-accurate xp, stored fp32. grid (6144, 2) x 256.
// ---------------------------------------------------------------------------
__global__ __launch_bounds__(256) void xp_mfma(
    const __half* __restrict__ xhi, const __half* __restrict__ xlo,
    const __half* __restrict__ whi, const __half* __restrict__ wlo,
    fp bih_c, fp bih_p, float* __restrict__ xp)
{
  int g = blockIdx.y;
  const _Float16* xh = (const _Float16*)xhi + (size_t)g * 8192 * II;
  const _Float16* xl = (const _Float16*)xlo + (size_t)g * 8192 * II;
  const _Float16* wh = (const _Float16*)whi + (size_t)g * 768 * II;
  const _Float16* wl = (const _Float16*)wlo + (size_t)g * 768 * II;
  fp bih = g ? bih_p : bih_c;
  float* xpo = xp + (size_t)g * 8192 * 768;

  int wave = blockIdx.x * 4 + (threadIdx.x >> 6);
  int lane = threadIdx.x & 63;
  int mt = wave / 48, nt = wave - mt * 48;   // 512 x 48 tiles
  int m0 = mt << 4, n0 = nt << 4;
  int lm = lane & 15, q = lane >> 4;

  size_t aoff = (size_t)(m0 + lm) * II + q * 8;
  size_t boff = (size_t)(n0 + lm) * II + q * 8;
  const f16x8* ah = (const f16x8*)(xh + aoff);
  const f16x8* al = (const f16x8*)(xl + aoff);
  const f16x8* bh = (const f16x8*)(wh + boff);
  const f16x8* bl = (const f16x8*)(wl + boff);
  f32x4 acc = {0.f, 0.f, 0.f, 0.f};
#pragma unroll
  for (int kk = 0; kk < 4; ++kk) {
    f16x8 a = ah[kk * 4], b = bh[kk * 4];
    acc = __builtin_amdgcn_mfma_f32_16x16x32_f16(a, b, acc, 0, 0, 0);
    acc = __builtin_amdgcn_mfma_f32_16x16x32_f16(al[kk * 4], b, acc, 0, 0, 0);
    acc = __builtin_amdgcn_mfma_f32_16x16x32_f16(a, bl[kk * 4], acc, 0, 0, 0);
  }
  float bias = bih[n0 + lm];
#pragma unroll
  for (int r = 0; r < 4; ++r)
    xpo[(size_t)(m0 + q * 4 + r) * 768 + n0 + lm] = acc[r] + bias;
}

// ---------------------------------------------------------------------------
// fully-fused MPNN: one block per molecule (<=14 atoms).
// ---------------------------------------------------------------------------
__global__ __launch_bounds__(256) void mpnn_mol(
    const int* __restrict__ fingerprints, fp embed_fp, fp adj,
    const int* __restrict__ mstart, fp w_g0, fp b_g0, fp w_g1, fp b_g1,
    float* __restrict__ mol)
{
  int m = blockIdx.x, tid = threadIdx.x;
  int a0 = mstart[m], a1 = mstart[m + 1];
  int sz = a1 - a0;
  if (sz < 0) sz = 0;
  if (sz > 14) sz = 14;

  __shared__ float v[14][260];
  __shared__ float adjb[14][16];

#pragma unroll
  for (int i = 0; i < 14; ++i) {
    float val = 0.f;
    if (i < sz) {
      int f = fingerprints[a0 + i] & 1023;
      val = embed_fp[(size_t)f * HH + tid];
    }
    v[i][tid] = val;
  }
  if (tid < 224) {
    int i = tid >> 4, jj = tid & 15;
    float a = 0.f;
    if (i < sz && jj < sz)
      a = adj[(size_t)(a0 + i) * NATOMS_N + a0 + jj];
    adjb[i][jj] = a;
  }
  __syncthreads();

  float acc[14];
  for (int rd = 0; rd < 2; ++rd) {
    const float* wp0 = (rd ? w_g1 : w_g0) + tid;
#pragma unroll
    for (int i = 0; i < 14; ++i) acc[i] = 0.f;
    for (int k = 0; k < HH; k += 4) {
      float w0 = wp0[(size_t)k * HH];
      float w1 = wp0[(size_t)(k + 1) * HH];
      float w2 = wp0[(size_t)(k + 2) * HH];
      float w3 = wp0[(size_t)(k + 3) * HH];
#pragma unroll
      for (int i = 0; i < 14; ++i) {
        float4 vv = *(const float4*)&v[i][k];
        acc[i] = fmaf(vv.x, w0, acc[i]);
        acc[i] = fmaf(vv.y, w1, acc[i]);
        acc[i] = fmaf(vv.z, w2, acc[i]);
        acc[i] = fmaf(vv.w, w3, acc[i]);
      }
    }
    float bias = (rd ? b_g1 : b_g0)[tid];
    float hreg[14];
#pragma unroll
    for (int i = 0; i < 14; ++i) hreg[i] = fmaxf(acc[i] + bias, 0.f);
#pragma unroll
    for (int i = 0; i < 14; ++i) {
      float s = hreg[i];
#pragma unroll
      for (int jj = 0; jj < 14; ++jj) s = fmaf(adjb[i][jj], hreg[jj], s);
      acc[i] = s;
    }
    if (rd == 0) {
      __syncthreads();
#pragma unroll
      for (int i = 0; i < 14; ++i) v[i][tid] = acc[i];
      __syncthreads();
    }
  }
  float msum = 0.f;
#pragma unroll
  for (int i = 0; i < 14; ++i) if (i < sz) msum += acc[i];
  mol[(size_t)m * HH + tid] = msum;
}

// ---------------------------------------------------------------------------
// mpnn_emb^T[h][d] = sum_m avg[d][m] * mol[m][h]
// ---------------------------------------------------------------------------
__global__ __launch_bounds__(256) void mpnn_emb_k(
    fp avg, const float* __restrict__ mol, float* __restrict__ embT)
{
  int d = blockIdx.x, tid = threadIdx.x;
  float acc = 0.f;
  for (int m = 0; m < NMOL_N; ++m)
    acc += avg[d * NMOL_N + m] * mol[(size_t)m * HH + tid];
  embT[(size_t)tid * LBL + d] = acc;
}

// ---------------------------------------------------------------------------
// GRU v9: register-persistent-weight MFMA GRU — v8 + 3 counter-driven fixes:
// (1) __launch_bounds__(512, 2): 2 waves/SIMD -> 256-VGPR budget so the
//     192-VGPR Bf weight array STAYS in registers (v8: VGPR_Count=128 ->
//     ~120 regs spilled; every step re-read ~768 B/thread from scratch —
//     the exact L2-traffic regression this design was meant to remove).
// (2) hbuf rows padded 256->264 f16 (528-B stride): b128 A-frag reads get
//     distinct start-banks per 8-lane phase -> conflict-free (v8: 4.19M
//     SQ_LDS_BANK_CONFLICT from 512-B power-of-2 stride).
// (3) xpl rows padded 768->772 f32: gate-phase reads 4-way -> 2-way (free).
//     Padding is gload_lds-safe: each wave's 64 slots sit inside one
//     192-slot row (192 = 3*64), so dest stays linear within the row.
// Also merged the two c-halves into one kf loop: 1 A ds_read feeds 6 MFMAs
// (6 independent chains hide MFMA latency; halves A-reads).
// ---------------------------------------------------------------------------
__global__ __launch_bounds__(512, 2) void gru_mfma(
    fp xp, fp whh_c, fp whh_p, fp bhh_c, fp bhh_p,
    float* __restrict__ hcat, const int* __restrict__ idxv)
{
  int blk = blockIdx.x;                // 32 blocks
  int g = blk >> 4;                    // 0 = cond, 1 = proc
  int b0 = (blk & 15) << 4;            // batch tile base
  int tid = threadIdx.x;
  int w = tid >> 6;                    // wave 0..7
  int l = tid & 63;
  int lm = l & 15, q = l >> 4;
  int jb = w * 32;                     // wave j-base

  fp whh = g ? whh_p : whh_c;
  fp bhh = g ? bhh_p : bhh_c;
  const float* xpg = xp + (size_t)g * 8192 * 768;

  __shared__ _Float16 hbuf[2][16][264];   // fp16 h mirror, padded rows
  __shared__ float xpl[2][16 * 772];      // staged xp rows, padded rows

  // zero h mirror buffer 0 (16*264 halfs = 2112 dwords, pad included)
  {
    unsigned* hz = (unsigned*)&hbuf[0][0][0];
    for (int i = tid; i < 2112; i += 512) hz[i] = 0u;
  }

  // ---- persistent fp16 weight fragments Bf[gate][c-half][kfrag] (192 VGPR)
  f16x8 Bf[3][2][8];
#pragma unroll
  for (int G = 0; G < 3; ++G)
#pragma unroll
    for (int c = 0; c < 2; ++c) {
      const float* src = whh + (size_t)(G * 256 + jb + c * 16 + lm) * 256 + q * 8;
#pragma unroll
      for (int kf = 0; kf < 8; ++kf) {
        float4 u0 = *(const float4*)(src + kf * 32);
        float4 u1 = *(const float4*)(src + kf * 32 + 4);
        f16x8 f;
        f[0] = (_Float16)u0.x; f[1] = (_Float16)u0.y;
        f[2] = (_Float16)u0.z; f[3] = (_Float16)u0.w;
        f[4] = (_Float16)u1.x; f[5] = (_Float16)u1.y;
        f[6] = (_Float16)u1.z; f[7] = (_Float16)u1.w;
        Bf[G][c][kf] = f;
      }
    }

  float bias[3][2];
#pragma unroll
  for (int G = 0; G < 3; ++G) {
    bias[G][0] = bhh[G * 256 + jb + lm];
    bias[G][1] = bhh[G * 256 + jb + 16 + lm];
  }
  int idxr[4];
#pragma unroll
  for (int rr = 0; rr < 4; ++rr) idxr[rr] = idxv[b0 + q * 4 + rr];

  float hold[2][4] = {{0.f, 0.f, 0.f, 0.f}, {0.f, 0.f, 0.f, 0.f}};

  // xp staging: 16 rows x 192 16B-slots; 6 issues/thread. Row stride padded
  // to 772 f32; each wave's 64 slots stay inside one row -> linear dest ok.
  auto stage = [&](int t, int buf) {
    float* dstbase = &xpl[buf][0];
#pragma unroll
    for (int i = 0; i < 6; ++i) {
      int gi = i * 512 + tid;
      int row = gi / 192;
      int c16 = gi - row * 192;
      const float* src = xpg + ((size_t)(b0 + row) * SS + t) * 768 + c16 * 4;
#if __has_builtin(__builtin_amdgcn_global_load_lds)
      int ubase = i * 512 + (tid & 0x1C0);       // wave-uniform slot base
      int urow = ubase / 192;
      int uc16 = ubase - urow * 192;
      __builtin_amdgcn_global_load_lds(
          (const __attribute__((address_space(1))) void*)src,
          (__attribute__((address_space(3))) void*)(dstbase + urow * 772 + uc16 * 4),
          16, 0, 0);
#else
      *(float4*)(dstbase + row * 772 + c16 * 4) = *(const float4*)src;
#endif
    }
  };

  stage(0, 0);
  __syncthreads();   // h mirror zeroed + xp[0] staged (barrier drains vmcnt)

  for (int t = 0; t < SS; ++t) {
    int p = t & 1;
    if (t + 1 < SS) stage(t + 1, p ^ 1);   // prefetch next step's xp

    const _Float16* hb = &hbuf[p][0][0];
    f32x4 a0r = {0.f, 0.f, 0.f, 0.f}, a0z = {0.f, 0.f, 0.f, 0.f},
          a0n = {0.f, 0.f, 0.f, 0.f}, a1r = {0.f, 0.f, 0.f, 0.f},
          a1z = {0.f, 0.f, 0.f, 0.f}, a1n = {0.f, 0.f, 0.f, 0.f};
#pragma unroll
    for (int kf = 0; kf < 8; ++kf) {
      f16x8 a = *(const f16x8*)(hb + lm * 264 + kf * 32 + q * 8);
      a0r = __builtin_amdgcn_mfma_f32_16x16x32_f16(a, Bf[0][0][kf], a0r, 0, 0, 0);
      a0z = __builtin_amdgcn_mfma_f32_16x16x32_f16(a, Bf[1][0][kf], a0z, 0, 0, 0);
      a0n = __builtin_amdgcn_mfma_f32_16x16x32_f16(a, Bf[2][0][kf], a0n, 0, 0, 0);
      a1r = __builtin_amdgcn_mfma_f32_16x16x32_f16(a, Bf[0][1][kf], a1r, 0, 0, 0);
      a1z = __builtin_amdgcn_mfma_f32_16x16x32_f16(a, Bf[1][1][kf], a1z, 0, 0, 0);
      a1n = __builtin_amdgcn_mfma_f32_16x16x32_f16(a, Bf[2][1][kf], a1n, 0, 0, 0);
    }
    const float* xpb = &xpl[p][0];
#pragma unroll
    for (int c = 0; c < 2; ++c) {
      f32x4 vr = (c == 0) ? a0r : a1r;
      f32x4 vz = (c == 0) ? a0z : a1z;
      f32x4 vn = (c == 0) ? a0n : a1n;
      int j = jb + c * 16 + lm;
#pragma unroll
      for (int rr = 0; rr < 4; ++rr) {
        int m = q * 4 + rr;
        float r = sigm(xpb[m * 772 + j] + vr[rr] + bias[0][c]);
        float z = sigm(xpb[m * 772 + 256 + j] + vz[rr] + bias[1][c]);
        float n = tanhf(xpb[m * 772 + 512 + j] + r * (vn[rr] + bias[2][c]));
        float hnew = (1.f - z) * n + z * hold[c][rr];
        hold[c][rr] = hnew;
        hbuf[p ^ 1][m][j] = (_Float16)hnew;   // fp16 mirror for next step
        if (t == idxr[rr])
          hcat[(size_t)(b0 + m) * 512 + g * 256 + j] = fmaxf(hnew, 0.f);
      }
    }
    __syncthreads();   // h writes + xp prefetch visible; all reads drained
  }
}

// ---------------------------------------------------------------------------
// fp32 GEMM for query: C[M,N] = A[M,K] @ W[K,N] + bias
// ---------------------------------------------------------------------------
__global__ __launch_bounds__(256) void gemm_f32(
    const float* __restrict__ A, fp W, fp bias, float* __restrict__ C,
    int M, int N, int K)
{
  int ntiles = N >> 4;
  int mt = blockIdx.x / ntiles, nt = blockIdx.x - mt * ntiles;
  int m0 = mt << 4, n0 = nt << 4;
  int tid = threadIdx.x;
  int ni = tid & 15, mi = tid >> 4;
  __shared__ float As[16][68];
  float acc = 0.f;
  for (int k0 = 0; k0 < K; k0 += 64) {
    __syncthreads();
    for (int i = tid; i < 1024; i += 256) {
      int r = i >> 6, kk = i & 63;
      As[r][kk] = A[(size_t)(m0 + r) * K + k0 + kk];
    }
    __syncthreads();
    const float* wp = W + (size_t)k0 * N + n0 + ni;
#pragma unroll 4
    for (int kk = 0; kk < 64; ++kk)
      acc = fmaf(As[mi][kk], wp[(size_t)kk * N], acc);
  }
  acc += bias[n0 + ni];
  C[(size_t)(m0 + mi) * N + n0 + ni] = acc;
}

// ---------------------------------------------------------------------------
// fused tail per batch row: match/x2/LN (mpnn_att) + bip/masked-linear + mul
// ---------------------------------------------------------------------------
__global__ __launch_bounds__(256) void tail_fused(
    const float* __restrict__ query, const float* __restrict__ embT,
    fp w_out, fp b_out, fp gamma, fp beta,
    fp w_bip, fp b_bip, const float* __restrict__ mw,
    float* __restrict__ out)
{
  int b = blockIdx.x, tid = threadIdx.x;
  __shared__ float q[HH];
  __shared__ float mrow[LBL];
  __shared__ float bips[NSUBS];
  __shared__ float red[256];
  q[tid] = query[(size_t)b * HH + tid];
  __syncthreads();
  if (tid < LBL) {
    float acc = 0.f;
    for (int k = 0; k < HH; ++k) acc += q[k] * embT[(size_t)k * LBL + tid];
    mrow[tid] = sigm(acc);
  }
  for (int s = tid; s < NSUBS; s += 256) {
    float acc = b_bip[s];
    for (int k = 0; k < HH; ++k) acc += q[k] * w_bip[(size_t)k * NSUBS + s];
    bips[s] = acc;
  }
  __syncthreads();
  float x2 = 0.f;
  if (tid < LBL) {
    float acc = b_out[tid] + mrow[tid];
    for (int jj = 0; jj < LBL; ++jj) acc += mrow[jj] * w_out[jj * LBL + tid];
    x2 = acc;
  }
  red[tid] = (tid < LBL) ? x2 : 0.f;
  __syncthreads();
  for (int s = 128; s > 0; s >>= 1) {
    if (tid < s) red[tid] += red[tid + s];
    __syncthreads();
  }
  float mu = red[0] / (float)LBL;
  __syncthreads();
  float dv = (tid < LBL) ? (x2 - mu) : 0.f;
  red[tid] = dv * dv;
  __syncthreads();
  for (int s = 128; s > 0; s >>= 1) {
    if (tid < s) red[tid] += red[tid + s];
    __syncthreads();
  }
  float var = red[0] / (float)LBL;
  if (tid < LBL) {
    float matt = (x2 - mu) * rsqrtf(var + 1e-5f) * gamma[tid] + beta[tid];
    float acc = 0.f;
    for (int s = 0; s < NSUBS; ++s) acc += bips[s] * mw[(size_t)s * LBL + tid];
    out[(size_t)b * LBL + tid] = acc * matt;
  }
}

// ---------------------------------------------------------------------------
extern "C" void kernel_launch(void* const* d_in, const int* in_sizes, int n_in,
                              void* d_out, int out_size, void* d_ws, size_t ws_size,
                              hipStream_t stream)
{
  fp x_c   = (fp)d_in[0];
  fp x_p   = (fp)d_in[1];
  const int* mask = (const int*)d_in[2];
  fp wih_c = (fp)d_in[3];
  fp whh_c = (fp)d_in[4];
  fp bih_c = (fp)d_in[5];
  fp bhh_c = (fp)d_in[6];
  fp wih_p = (fp)d_in[7];
  fp whh_p = (fp)d_in[8];
  fp bih_p = (fp)d_in[9];
  fp bhh_p = (fp)d_in[10];
  fp w_query = (fp)d_in[11];
  fp b_query = (fp)d_in[12];
  fp w_bip = (fp)d_in[13];
  fp b_bip = (fp)d_in[14];
  fp w_masklin = (fp)d_in[15];
  fp ddi = (fp)d_in[16];
  fp embed_fp = (fp)d_in[17];
  const int* fingerprints = (const int*)d_in[18];
  fp adj = (fp)d_in[19];
  const int* seg = (const int*)d_in[20];
  fp w_g0 = (fp)d_in[21];
  fp b_g0 = (fp)d_in[22];
  fp w_g1 = (fp)d_in[23];
  fp b_g1 = (fp)d_in[24];
  fp avg = (fp)d_in[25];
  fp w_out = (fp)d_in[26];
  fp b_out = (fp)d_in[27];
  fp gamma = (fp)d_in[28];
  fp beta = (fp)d_in[29];
  float* out = (float*)d_out;

  char* w = (char*)d_ws;
  size_t off = 0;
  auto alloc = [&](size_t bytes) -> void* {
    void* p = w + off;
    off = (off + bytes + 255) & ~(size_t)255;
    return p;
  };

  float* xp   = (float*)alloc((size_t)2 * 8192 * 768 * 4);    // 50.3 MB
  __half* xhi = (__half*)alloc((size_t)2 * 8192 * 128 * 2);   // 4.2 MB
  __half* xlo = (__half*)alloc((size_t)2 * 8192 * 128 * 2);   // 4.2 MB
  __half* whi = (__half*)alloc((size_t)2 * 768 * 128 * 2);    // 0.4 MB
  __half* wlo = (__half*)alloc((size_t)2 * 768 * 128 * 2);    // 0.4 MB
  float* mol  = (float*)alloc((size_t)NMOL_N * HH * 4);
  float* embT = (float*)alloc((size_t)HH * LBL * 4);
  float* hcat = (float*)alloc((size_t)BB * 2 * HH * 4);
  float* query = (float*)alloc((size_t)BB * HH * 4);
  float* mw   = (float*)alloc((size_t)NSUBS * LBL * 4);
  int* idxv   = (int*)alloc(256 * 4);
  int* mstart = (int*)alloc((NMOL_N + 1) * 4);

  prep_kernel<<<1126, 256, 0, stream>>>(mask, idxv, seg, mstart, w_masklin,
                                        ddi, mw, x_c, x_p, xhi, xlo,
                                        wih_c, wih_p, whi, wlo);

  xp_mfma<<<dim3(6144, 2), 256, 0, stream>>>(xhi, xlo, whi, wlo,
                                             bih_c, bih_p, xp);

  mpnn_mol<<<NMOL_N, 256, 0, stream>>>(fingerprints, embed_fp, adj, mstart,
                                       w_g0, b_g0, w_g1, b_g1, mol);
  mpnn_emb_k<<<LBL, 256, 0, stream>>>(avg, mol, embT);

  gru_mfma<<<32, 512, 0, stream>>>(xp, whh_c, whh_p, bhh_c, bhh_p, hcat, idxv);

  gemm_f32<<<256, 256, 0, stream>>>(hcat, w_query, b_query, query, BB, HH, 2 * HH);
  tail_fused<<<BB, 256, 0, stream>>>(query, embT, w_out, b_out, gamma, beta,
                                     w_bip, b_bip, mw, out);
}

// Round 11
// 912.811 us; speedup vs baseline: 1.0181x; 1.0181x over previous
//
#include <hip/hip_runtime.h>
#include <hip/hip_bf16.h>
#include <hip/hip_fp16.h>

#define BB 256
#define SS 32
#define II 128
#define HH 256
#define LBL 200
#define NSUBS 491
#define NATOMS_N 8000
#define NMOL_N 600

typedef const float* fp;
typedef __attribute__((ext_vector_type(8))) _Float16 f16x8;
typedef __attribute__((ext_vector_type(4))) float f32x4;

__device__ __forceinline__ float sigm(float x) { return 1.f / (1.f + expf(-x)); }

// ---------------------------------------------------------------------------
// prep (1126 blocks): idxv, mstart, masked w_masklin, and SPLIT-fp16
// conversions of x and w_ih (hi + residual lo) for the xp matrix-core GEMM.
// ---------------------------------------------------------------------------
__global__ __launch_bounds__(256) void prep_kernel(
    const int* __restrict__ mask, int* __restrict__ idxv,
    const int* __restrict__ seg, int* __restrict__ mstart,
    fp w_masklin, fp ddi, float* __restrict__ mw,
    fp x_c, fp x_p, __half* __restrict__ xhi, __half* __restrict__ xlo,
    fp wih_c, fp wih_p, __half* __restrict__ whi, __half* __restrict__ wlo)
{
  int bx = blockIdx.x, tid = threadIdx.x;
  if (bx == 0) {                         // idx[b] = clamp(sum(mask[b,:]) - 1)
    int s = 0;
    const int* mrow = mask + tid * SS;
    for (int t = 0; t < SS; ++t) s += mrow[t];
    s -= 1;
    if (s < 0) s = 0;
    if (s > SS - 1) s = SS - 1;
    idxv[tid] = s;
  } else if (bx == 1) {                  // mstart[m] = lower_bound(seg, m)
    for (int m = tid; m <= NMOL_N; m += 256) {
      if (m == NMOL_N) { mstart[m] = NATOMS_N; continue; }
      int lo = 0, hi = NATOMS_N;
      while (lo < hi) {
        int mid = (lo + hi) >> 1;
        if (seg[mid] < m) lo = mid + 1; else hi = mid;
      }
      mstart[m] = lo;
    }
  } else if (bx < 6) {                   // mw[s][l] = w_masklin[s][l]*ddi[l][s]
    for (int o = (bx - 2) * 256 + tid; o < NSUBS * LBL; o += 4 * 256) {
      int s = o / LBL, l = o - s * LBL;
      mw[o] = w_masklin[o] * ddi[l * NSUBS + s];
    }
  } else if (bx < 1030) {                // x -> fp16 hi+lo (2 x 1048576)
    int base = (bx - 6) * 2048;
    for (int o = base + tid; o < base + 2048; o += 256) {
      float v = (o < 1048576) ? x_c[o] : x_p[o - 1048576];
      __half h = __float2half(v);
      xhi[o] = h;
      xlo[o] = __float2half(v - __half2float(h));
    }
  } else {                               // w_ih -> fp16 hi+lo (2 x 98304)
    int base = (bx - 1030) * 2048;
    for (int o = base + tid; o < base + 2048; o += 256) {
      float v = (o < 98304) ? wih_c[o] : wih_p[o - 98304];
      __half h = __float2half(v);
      whi[o] = h;
      wlo[o] = __float2half(v - __half2float(h));
    }
  }
}

// ---------------------------------------------------------------------------
// xp = x @ w_ih.T + b_ih via SPLIT-fp16 MFMA (3 chains: hi*whi + lo*whi +
// hi*wlo) -> fp32-accurate xp, stored fp32. grid (6144, 2) x 256.
// ---------------------------------------------------------------------------
__global__ __launch_bounds__(256) void xp_mfma(
    const __half* __restrict__ xhi, const __half* __restrict__ xlo,
    const __half* __restrict__ whi, const __half* __restrict__ wlo,
    fp bih_c, fp bih_p, float* __restrict__ xp)
{
  int g = blockIdx.y;
  const _Float16* xh = (const _Float16*)xhi + (size_t)g * 8192 * II;
  const _Float16* xl = (const _Float16*)xlo + (size_t)g * 8192 * II;
  const _Float16* wh = (const _Float16*)whi + (size_t)g * 768 * II;
  const _Float16* wl = (const _Float16*)wlo + (size_t)g * 768 * II;
  fp bih = g ? bih_p : bih_c;
  float* xpo = xp + (size_t)g * 8192 * 768;

  int wave = blockIdx.x * 4 + (threadIdx.x >> 6);
  int lane = threadIdx.x & 63;
  int mt = wave / 48, nt = wave - mt * 48;   // 512 x 48 tiles
  int m0 = mt << 4, n0 = nt << 4;
  int lm = lane & 15, q = lane >> 4;

  size_t aoff = (size_t)(m0 + lm) * II + q * 8;
  size_t boff = (size_t)(n0 + lm) * II + q * 8;
  const f16x8* ah = (const f16x8*)(xh + aoff);
  const f16x8* al = (const f16x8*)(xl + aoff);
  const f16x8* bh = (const f16x8*)(wh + boff);
  const f16x8* bl = (const f16x8*)(wl + boff);
  f32x4 acc = {0.f, 0.f, 0.f, 0.f};
#pragma unroll
  for (int kk = 0; kk < 4; ++kk) {
    f16x8 a = ah[kk * 4], b = bh[kk * 4];
    acc = __builtin_amdgcn_mfma_f32_16x16x32_f16(a, b, acc, 0, 0, 0);
    acc = __builtin_amdgcn_mfma_f32_16x16x32_f16(al[kk * 4], b, acc, 0, 0, 0);
    acc = __builtin_amdgcn_mfma_f32_16x16x32_f16(a, bl[kk * 4], acc, 0, 0, 0);
  }
  float bias = bih[n0 + lm];
#pragma unroll
  for (int r = 0; r < 4; ++r)
    xpo[(size_t)(m0 + q * 4 + r) * 768 + n0 + lm] = acc[r] + bias;
}

// ---------------------------------------------------------------------------
// fully-fused MPNN: one block per molecule (<=14 atoms).
// ---------------------------------------------------------------------------
__global__ __launch_bounds__(256) void mpnn_mol(
    const int* __restrict__ fingerprints, fp embed_fp, fp adj,
    const int* __restrict__ mstart, fp w_g0, fp b_g0, fp w_g1, fp b_g1,
    float* __restrict__ mol)
{
  int m = blockIdx.x, tid = threadIdx.x;
  int a0 = mstart[m], a1 = mstart[m + 1];
  int sz = a1 - a0;
  if (sz < 0) sz = 0;
  if (sz > 14) sz = 14;

  __shared__ float v[14][260];
  __shared__ float adjb[14][16];

#pragma unroll
  for (int i = 0; i < 14; ++i) {
    float val = 0.f;
    if (i < sz) {
      int f = fingerprints[a0 + i] & 1023;
      val = embed_fp[(size_t)f * HH + tid];
    }
    v[i][tid] = val;
  }
  if (tid < 224) {
    int i = tid >> 4, jj = tid & 15;
    float a = 0.f;
    if (i < sz && jj < sz)
      a = adj[(size_t)(a0 + i) * NATOMS_N + a0 + jj];
    adjb[i][jj] = a;
  }
  __syncthreads();

  float acc[14];
  for (int rd = 0; rd < 2; ++rd) {
    const float* wp0 = (rd ? w_g1 : w_g0) + tid;
#pragma unroll
    for (int i = 0; i < 14; ++i) acc[i] = 0.f;
    for (int k = 0; k < HH; k += 4) {
      float w0 = wp0[(size_t)k * HH];
      float w1 = wp0[(size_t)(k + 1) * HH];
      float w2 = wp0[(size_t)(k + 2) * HH];
      float w3 = wp0[(size_t)(k + 3) * HH];
#pragma unroll
      for (int i = 0; i < 14; ++i) {
        float4 vv = *(const float4*)&v[i][k];
        acc[i] = fmaf(vv.x, w0, acc[i]);
        acc[i] = fmaf(vv.y, w1, acc[i]);
        acc[i] = fmaf(vv.z, w2, acc[i]);
        acc[i] = fmaf(vv.w, w3, acc[i]);
      }
    }
    float bias = (rd ? b_g1 : b_g0)[tid];
    float hreg[14];
#pragma unroll
    for (int i = 0; i < 14; ++i) hreg[i] = fmaxf(acc[i] + bias, 0.f);
#pragma unroll
    for (int i = 0; i < 14; ++i) {
      float s = hreg[i];
#pragma unroll
      for (int jj = 0; jj < 14; ++jj) s = fmaf(adjb[i][jj], hreg[jj], s);
      acc[i] = s;
    }
    if (rd == 0) {
      __syncthreads();
#pragma unroll
      for (int i = 0; i < 14; ++i) v[i][tid] = acc[i];
      __syncthreads();
    }
  }
  float msum = 0.f;
#pragma unroll
  for (int i = 0; i < 14; ++i) if (i < sz) msum += acc[i];
  mol[(size_t)m * HH + tid] = msum;
}

// ---------------------------------------------------------------------------
// mpnn_emb^T[h][d] = sum_m avg[d][m] * mol[m][h]
// ---------------------------------------------------------------------------
__global__ __launch_bounds__(256) void mpnn_emb_k(
    fp avg, const float* __restrict__ mol, float* __restrict__ embT)
{
  int d = blockIdx.x, tid = threadIdx.x;
  float acc = 0.f;
  for (int m = 0; m < NMOL_N; ++m)
    acc += avg[d * NMOL_N + m] * mol[(size_t)m * HH + tid];
  embT[(size_t)tid * LBL + d] = acc;
}

// ---------------------------------------------------------------------------
// GRU v10: register-persistent-weight MFMA GRU — v9 diagnosis: VGPR_Count
// stuck at 128 in BOTH v8 (no hint) and v9 (hint=2) => the f16x8 Bf[3][2][8]
// ALLOCA was never promoted to registers (SROA/promote-alloca gave up on the
// 768-B aggregate); weights lived in scratch, 48 serialized ~300-cyc reloads
// per step = the measured 225 us. Two fixes:
// (1) 48 individually-NAMED f16x8 values (macro-generated) — SSA scalars,
//     cannot be demoted to scratch without visible spill code.
// (2) __launch_bounds__(512, 1) — safe under either arg-2 interpretation
//     (waves/EU=1 -> cap 512, structurally clamped to 256 by 8-wave block;
//     CUDA-style blocks/CU=1 -> cap 256). v9's "2" caps at 128 if hipcc
//     reads it CUDA-style.
// Two c-half passes (3 live acc chains, not 6) cut peak pressure:
// ~192 wt + 12 acc + ~45 misc ~= 250 <= 256.
// hbuf rows 264 f16 / xpl rows 772 f32 padding kept (4.19M -> 262K
// bank conflicts, verified r6).
// ---------------------------------------------------------------------------
#define DECLB(G,C,K) f16x8 Bf_##G##_##C##_##K;
#define LOADB(G,C,K) Bf_##G##_##C##_##K = ldB(G, C, K);
#define FMA3(K,C) { \
    f16x8 a = *(const f16x8*)(hb + lm * 264 + K * 32 + q * 8); \
    ar = __builtin_amdgcn_mfma_f32_16x16x32_f16(a, Bf_0_##C##_##K, ar, 0, 0, 0); \
    az = __builtin_amdgcn_mfma_f32_16x16x32_f16(a, Bf_1_##C##_##K, az, 0, 0, 0); \
    an = __builtin_amdgcn_mfma_f32_16x16x32_f16(a, Bf_2_##C##_##K, an, 0, 0, 0); }
#define GATES(C) { \
    int j = jb + C * 16 + lm; \
    _Pragma("unroll") \
    for (int rr = 0; rr < 4; ++rr) { \
      int m = q * 4 + rr; \
      float r = sigm(xpb[m * 772 + j] + ar[rr] + br##C); \
      float z = sigm(xpb[m * 772 + 256 + j] + az[rr] + bz##C); \
      float n = tanhf(xpb[m * 772 + 512 + j] + r * (an[rr] + bn##C)); \
      float hnew = (1.f - z) * n + z * hold##C[rr]; \
      hold##C[rr] = hnew; \
      hw[m * 264 + j] = (_Float16)hnew; \
      if (t == idxr[rr]) \
        hcat[(size_t)(b0 + m) * 512 + g * 256 + j] = fmaxf(hnew, 0.f); \
    } }

__global__ __launch_bounds__(512, 1) void gru_mfma(
    fp xp, fp whh_c, fp whh_p, fp bhh_c, fp bhh_p,
    float* __restrict__ hcat, const int* __restrict__ idxv)
{
  int blk = blockIdx.x;                // 32 blocks
  int g = blk >> 4;                    // 0 = cond, 1 = proc
  int b0 = (blk & 15) << 4;            // batch tile base
  int tid = threadIdx.x;
  int w = tid >> 6;                    // wave 0..7
  int l = tid & 63;
  int lm = l & 15, q = l >> 4;
  int jb = w * 32;                     // wave j-base

  fp whh = g ? whh_p : whh_c;
  fp bhh = g ? bhh_p : bhh_c;
  const float* xpg = xp + (size_t)g * 8192 * 768;

  __shared__ _Float16 hbuf[2][16][264];   // fp16 h mirror, padded rows
  __shared__ float xpl[2][16 * 772];      // staged xp rows, padded rows

  // zero h mirror buffer 0 (16*264 halfs = 2112 dwords, pad included)
  {
    unsigned* hz = (unsigned*)&hbuf[0][0][0];
    for (int i = tid; i < 2112; i += 512) hz[i] = 0u;
  }

  auto ldB = [&](int G, int C, int kf) -> f16x8 {
    const float* src =
        whh + (size_t)(G * 256 + jb + C * 16 + lm) * 256 + kf * 32 + q * 8;
    float4 u0 = *(const float4*)(src);
    float4 u1 = *(const float4*)(src + 4);
    f16x8 f;
    f[0] = (_Float16)u0.x; f[1] = (_Float16)u0.y;
    f[2] = (_Float16)u0.z; f[3] = (_Float16)u0.w;
    f[4] = (_Float16)u1.x; f[5] = (_Float16)u1.y;
    f[6] = (_Float16)u1.z; f[7] = (_Float16)u1.w;
    return f;
  };

  // ---- 48 named persistent fp16 weight fragments (192 VGPRs as scalars)
  DECLB(0,0,0) DECLB(0,0,1) DECLB(0,0,2) DECLB(0,0,3)
  DECLB(0,0,4) DECLB(0,0,5) DECLB(0,0,6) DECLB(0,0,7)
  DECLB(1,0,0) DECLB(1,0,1) DECLB(1,0,2) DECLB(1,0,3)
  DECLB(1,0,4) DECLB(1,0,5) DECLB(1,0,6) DECLB(1,0,7)
  DECLB(2,0,0) DECLB(2,0,1) DECLB(2,0,2) DECLB(2,0,3)
  DECLB(2,0,4) DECLB(2,0,5) DECLB(2,0,6) DECLB(2,0,7)
  DECLB(0,1,0) DECLB(0,1,1) DECLB(0,1,2) DECLB(0,1,3)
  DECLB(0,1,4) DECLB(0,1,5) DECLB(0,1,6) DECLB(0,1,7)
  DECLB(1,1,0) DECLB(1,1,1) DECLB(1,1,2) DECLB(1,1,3)
  DECLB(1,1,4) DECLB(1,1,5) DECLB(1,1,6) DECLB(1,1,7)
  DECLB(2,1,0) DECLB(2,1,1) DECLB(2,1,2) DECLB(2,1,3)
  DECLB(2,1,4) DECLB(2,1,5) DECLB(2,1,6) DECLB(2,1,7)

  LOADB(0,0,0) LOADB(0,0,1) LOADB(0,0,2) LOADB(0,0,3)
  LOADB(0,0,4) LOADB(0,0,5) LOADB(0,0,6) LOADB(0,0,7)
  LOADB(1,0,0) LOADB(1,0,1) LOADB(1,0,2) LOADB(1,0,3)
  LOADB(1,0,4) LOADB(1,0,5) LOADB(1,0,6) LOADB(1,0,7)
  LOADB(2,0,0) LOADB(2,0,1) LOADB(2,0,2) LOADB(2,0,3)
  LOADB(2,0,4) LOADB(2,0,5) LOADB(2,0,6) LOADB(2,0,7)
  LOADB(0,1,0) LOADB(0,1,1) LOADB(0,1,2) LOADB(0,1,3)
  LOADB(0,1,4) LOADB(0,1,5) LOADB(0,1,6) LOADB(0,1,7)
  LOADB(1,1,0) LOADB(1,1,1) LOADB(1,1,2) LOADB(1,1,3)
  LOADB(1,1,4) LOADB(1,1,5) LOADB(1,1,6) LOADB(1,1,7)
  LOADB(2,1,0) LOADB(2,1,1) LOADB(2,1,2) LOADB(2,1,3)
  LOADB(2,1,4) LOADB(2,1,5) LOADB(2,1,6) LOADB(2,1,7)

  float br0 = bhh[jb + lm],       bz0 = bhh[256 + jb + lm];
  float bn0 = bhh[512 + jb + lm];
  float br1 = bhh[jb + 16 + lm],  bz1 = bhh[256 + jb + 16 + lm];
  float bn1 = bhh[512 + jb + 16 + lm];
  int idxr[4];
#pragma unroll
  for (int rr = 0; rr < 4; ++rr) idxr[rr] = idxv[b0 + q * 4 + rr];

  float hold0[4] = {0.f, 0.f, 0.f, 0.f};
  float hold1[4] = {0.f, 0.f, 0.f, 0.f};

  // xp staging: 16 rows x 192 16B-slots; 6 issues/thread. Row stride padded
  // to 772 f32; each wave's 64 slots stay inside one row -> linear dest ok.
  auto stage = [&](int t, int buf) {
    float* dstbase = &xpl[buf][0];
#pragma unroll
    for (int i = 0; i < 6; ++i) {
      int gi = i * 512 + tid;
      int row = gi / 192;
      int c16 = gi - row * 192;
      const float* src = xpg + ((size_t)(b0 + row) * SS + t) * 768 + c16 * 4;
#if __has_builtin(__builtin_amdgcn_global_load_lds)
      int ubase = i * 512 + (tid & 0x1C0);       // wave-uniform slot base
      int urow = ubase / 192;
      int uc16 = ubase - urow * 192;
      __builtin_amdgcn_global_load_lds(
          (const __attribute__((address_space(1))) void*)src,
          (__attribute__((address_space(3))) void*)(dstbase + urow * 772 + uc16 * 4),
          16, 0, 0);
#else
      *(float4*)(dstbase + row * 772 + c16 * 4) = *(const float4*)src;
#endif
    }
  };

  stage(0, 0);
  __syncthreads();   // h mirror zeroed + xp[0] staged (barrier drains vmcnt)

  for (int t = 0; t < SS; ++t) {
    int p = t & 1;
    if (t + 1 < SS) stage(t + 1, p ^ 1);   // prefetch next step's xp

    const _Float16* hb = &hbuf[p][0][0];
    const float* xpb = &xpl[p][0];
    _Float16* hw = &hbuf[p ^ 1][0][0];

    {  // c-half 0
      f32x4 ar = {0.f, 0.f, 0.f, 0.f};
      f32x4 az = {0.f, 0.f, 0.f, 0.f};
      f32x4 an = {0.f, 0.f, 0.f, 0.f};
      FMA3(0,0) FMA3(1,0) FMA3(2,0) FMA3(3,0)
      FMA3(4,0) FMA3(5,0) FMA3(6,0) FMA3(7,0)
      GATES(0)
    }
    {  // c-half 1
      f32x4 ar = {0.f, 0.f, 0.f, 0.f};
      f32x4 az = {0.f, 0.f, 0.f, 0.f};
      f32x4 an = {0.f, 0.f, 0.f, 0.f};
      FMA3(0,1) FMA3(1,1) FMA3(2,1) FMA3(3,1)
      FMA3(4,1) FMA3(5,1) FMA3(6,1) FMA3(7,1)
      GATES(1)
    }
    __syncthreads();   // h writes + xp prefetch visible; all reads drained
  }
}

// ---------------------------------------------------------------------------
// fp32 GEMM for query: C[M,N] = A[M,K] @ W[K,N] + bias
// ---------------------------------------------------------------------------
__global__ __launch_bounds__(256) void gemm_f32(
    const float* __restrict__ A, fp W, fp bias, float* __restrict__ C,
    int M, int N, int K)
{
  int ntiles = N >> 4;
  int mt = blockIdx.x / ntiles, nt = blockIdx.x - mt * ntiles;
  int m0 = mt << 4, n0 = nt << 4;
  int tid = threadIdx.x;
  int ni = tid & 15, mi = tid >> 4;
  __shared__ float As[16][68];
  float acc = 0.f;
  for (int k0 = 0; k0 < K; k0 += 64) {
    __syncthreads();
    for (int i = tid; i < 1024; i += 256) {
      int r = i >> 6, kk = i & 63;
      As[r][kk] = A[(size_t)(m0 + r) * K + k0 + kk];
    }
    __syncthreads();
    const float* wp = W + (size_t)k0 * N + n0 + ni;
#pragma unroll 4
    for (int kk = 0; kk < 64; ++kk)
      acc = fmaf(As[mi][kk], wp[(size_t)kk * N], acc);
  }
  acc += bias[n0 + ni];
  C[(size_t)(m0 + mi) * N + n0 + ni] = acc;
}

// ---------------------------------------------------------------------------
// fused tail per batch row: match/x2/LN (mpnn_att) + bip/masked-linear + mul
// ---------------------------------------------------------------------------
__global__ __launch_bounds__(256) void tail_fused(
    const float* __restrict__ query, const float* __restrict__ embT,
    fp w_out, fp b_out, fp gamma, fp beta,
    fp w_bip, fp b_bip, const float* __restrict__ mw,
    float* __restrict__ out)
{
  int b = blockIdx.x, tid = threadIdx.x;
  __shared__ float q[HH];
  __shared__ float mrow[LBL];
  __shared__ float bips[NSUBS];
  __shared__ float red[256];
  q[tid] = query[(size_t)b * HH + tid];
  __syncthreads();
  if (tid < LBL) {
    float acc = 0.f;
    for (int k = 0; k < HH; ++k) acc += q[k] * embT[(size_t)k * LBL + tid];
    mrow[tid] = sigm(acc);
  }
  for (int s = tid; s < NSUBS; s += 256) {
    float acc = b_bip[s];
    for (int k = 0; k < HH; ++k) acc += q[k] * w_bip[(size_t)k * NSUBS + s];
    bips[s] = acc;
  }
  __syncthreads();
  float x2 = 0.f;
  if (tid < LBL) {
    float acc = b_out[tid] + mrow[tid];
    for (int jj = 0; jj < LBL; ++jj) acc += mrow[jj] * w_out[jj * LBL + tid];
    x2 = acc;
  }
  red[tid] = (tid < LBL) ? x2 : 0.f;
  __syncthreads();
  for (int s = 128; s > 0; s >>= 1) {
    if (tid < s) red[tid] += red[tid + s];
    __syncthreads();
  }
  float mu = red[0] / (float)LBL;
  __syncthreads();
  float dv = (tid < LBL) ? (x2 - mu) : 0.f;
  red[tid] = dv * dv;
  __syncthreads();
  for (int s = 128; s > 0; s >>= 1) {
    if (tid < s) red[tid] += red[tid + s];
    __syncthreads();
  }
  float var = red[0] / (float)LBL;
  if (tid < LBL) {
    float matt = (x2 - mu) * rsqrtf(var + 1e-5f) * gamma[tid] + beta[tid];
    float acc = 0.f;
    for (int s = 0; s < NSUBS; ++s) acc += bips[s] * mw[(size_t)s * LBL + tid];
    out[(size_t)b * LBL + tid] = acc * matt;
  }
}

// ---------------------------------------------------------------------------
extern "C" void kernel_launch(void* const* d_in, const int* in_sizes, int n_in,
                              void* d_out, int out_size, void* d_ws, size_t ws_size,
                              hipStream_t stream)
{
  fp x_c   = (fp)d_in[0];
  fp x_p   = (fp)d_in[1];
  const int* mask = (const int*)d_in[2];
  fp wih_c = (fp)d_in[3];
  fp whh_c = (fp)d_in[4];
  fp bih_c = (fp)d_in[5];
  fp bhh_c = (fp)d_in[6];
  fp wih_p = (fp)d_in[7];
  fp whh_p = (fp)d_in[8];
  fp bih_p = (fp)d_in[9];
  fp bhh_p = (fp)d_in[10];
  fp w_query = (fp)d_in[11];
  fp b_query = (fp)d_in[12];
  fp w_bip = (fp)d_in[13];
  fp b_bip = (fp)d_in[14];
  fp w_masklin = (fp)d_in[15];
  fp ddi = (fp)d_in[16];
  fp embed_fp = (fp)d_in[17];
  const int* fingerprints = (const int*)d_in[18];
  fp adj = (fp)d_in[19];
  const int* seg = (const int*)d_in[20];
  fp w_g0 = (fp)d_in[21];
  fp b_g0 = (fp)d_in[22];
  fp w_g1 = (fp)d_in[23];
  fp b_g1 = (fp)d_in[24];
  fp avg = (fp)d_in[25];
  fp w_out = (fp)d_in[26];
  fp b_out = (fp)d_in[27];
  fp gamma = (fp)d_in[28];
  fp beta = (fp)d_in[29];
  float* out = (float*)d_out;

  char* w = (char*)d_ws;
  size_t off = 0;
  auto alloc = [&](size_t bytes) -> void* {
    void* p = w + off;
    off = (off + bytes + 255) & ~(size_t)255;
    return p;
  };

  float* xp   = (float*)alloc((size_t)2 * 8192 * 768 * 4);    // 50.3 MB
  __half* xhi = (__half*)alloc((size_t)2 * 8192 * 128 * 2);   // 4.2 MB
  __half* xlo = (__half*)alloc((size_t)2 * 8192 * 128 * 2);   // 4.2 MB
  __half* whi = (__half*)alloc((size_t)2 * 768 * 128 * 2);    // 0.4 MB
  __half* wlo = (__half*)alloc((size_t)2 * 768 * 128 * 2);    // 0.4 MB
  float* mol  = (float*)alloc((size_t)NMOL_N * HH * 4);
  float* embT = (float*)alloc((size_t)HH * LBL * 4);
  float* hcat = (float*)alloc((size_t)BB * 2 * HH * 4);
  float* query = (float*)alloc((size_t)BB * HH * 4);
  float* mw   = (float*)alloc((size_t)NSUBS * LBL * 4);
  int* idxv   = (int*)alloc(256 * 4);
  int* mstart = (int*)alloc((NMOL_N + 1) * 4);

  prep_kernel<<<1126, 256, 0, stream>>>(mask, idxv, seg, mstart, w_masklin,
                                        ddi, mw, x_c, x_p, xhi, xlo,
                                        wih_c, wih_p, whi, wlo);

  xp_mfma<<<dim3(6144, 2), 256, 0, stream>>>(xhi, xlo, whi, wlo,
                                             bih_c, bih_p, xp);

  mpnn_mol<<<NMOL_N, 256, 0, stream>>>(fingerprints, embed_fp, adj, mstart,
                                       w_g0, b_g0, w_g1, b_g1, mol);
  mpnn_emb_k<<<LBL, 256, 0, stream>>>(avg, mol, embT);

  gru_mfma<<<32, 512, 0, stream>>>(xp, whh_c, whh_p, bhh_c, bhh_p, hcat, idxv);

  gemm_f32<<<256, 256, 0, stream>>>(hcat, w_query, b_query, query, BB, HH, 2 * HH);
  tail_fused<<<BB, 256, 0, stream>>>(query, embT, w_out, b_out, gamma, beta,
                                     w_bip, b_bip, mw, out);
}

// Round 12
// 738.920 us; speedup vs baseline: 1.2577x; 1.2353x over previous
//
#include <hip/hip_runtime.h>
#include <hip/hip_bf16.h>
#include <hip/hip_fp16.h>

#define BB 256
#define SS 32
#define II 128
#define HH 256
#define LBL 200
#define NSUBS 491
#define NATOMS_N 8000
#define NMOL_N 600

typedef const float* fp;
typedef __attribute__((ext_vector_type(2))) _Float16 h2t;
typedef __attribute__((ext_vector_type(8))) _Float16 f16x8;
typedef __attribute__((ext_vector_type(4))) float f32x4;

__device__ __forceinline__ float sigm(float x) { return 1.f / (1.f + expf(-x)); }
__device__ __forceinline__ float hlo(unsigned u) {
  return __half2float(__ushort_as_half((unsigned short)(u & 0xffffu)));
}
__device__ __forceinline__ float hhi(unsigned u) {
  return __half2float(__ushort_as_half((unsigned short)(u >> 16)));
}

#if __has_builtin(__builtin_amdgcn_fdot2)
__device__ __forceinline__ float dot2u(unsigned ha, unsigned wa, float acc) {
  return __builtin_amdgcn_fdot2(__builtin_bit_cast(h2t, ha),
                                __builtin_bit_cast(h2t, wa), acc, false);
}
#else
__device__ __forceinline__ float dot2u(unsigned ha, unsigned wa, float acc) {
  acc = fmaf(hlo(ha), hlo(wa), acc);
  return fmaf(hhi(ha), hhi(wa), acc);
}
#endif

// ---------------------------------------------------------------------------
// prep (1190 blocks): idxv, mstart, masked w_masklin, fp16 uint4-packed GRU
// weights wQ (for gru_dot4), and SPLIT-fp16 conversions of x and w_ih.
// (Identical to the 810-us r1 baseline prep.)
// ---------------------------------------------------------------------------
__global__ __launch_bounds__(256) void prep_kernel(
    const int* __restrict__ mask, int* __restrict__ idxv,
    const int* __restrict__ seg, int* __restrict__ mstart,
    fp w_masklin, fp ddi, float* __restrict__ mw,
    fp whh_c, fp whh_p, uint4* __restrict__ wQ,
    fp x_c, fp x_p, __half* __restrict__ xhi, __half* __restrict__ xlo,
    fp wih_c, fp wih_p, __half* __restrict__ whi, __half* __restrict__ wlo)
{
  int bx = blockIdx.x, tid = threadIdx.x;
  if (bx == 0) {                         // idx[b] = clamp(sum(mask[b,:]) - 1)
    int s = 0;
    const int* mrow = mask + tid * SS;
    for (int t = 0; t < SS; ++t) s += mrow[t];
    s -= 1;
    if (s < 0) s = 0;
    if (s > SS - 1) s = SS - 1;
    idxv[tid] = s;
  } else if (bx == 1) {                  // mstart[m] = lower_bound(seg, m)
    for (int m = tid; m <= NMOL_N; m += 256) {
      if (m == NMOL_N) { mstart[m] = NATOMS_N; continue; }
      int lo = 0, hi = NATOMS_N;
      while (lo < hi) {
        int mid = (lo + hi) >> 1;
        if (seg[mid] < m) lo = mid + 1; else hi = mid;
      }
      mstart[m] = lo;
    }
  } else if (bx < 6) {                   // mw[s][l] = w_masklin[s][l]*ddi[l][s]
    for (int o = (bx - 2) * 256 + tid; o < NSUBS * LBL; o += 4 * 256) {
      int s = o / LBL, l = o - s * LBL;
      mw[o] = w_masklin[o] * ddi[l * NSUBS + s];
    }
  } else if (bx < 70) {                  // weight pack: one (g, kk8) per block
    int lin = bx - 6;                    // 0..63
    int g = lin >> 5;
    int kk8 = lin & 31;
    fp whh = g ? whh_p : whh_c;
    uint4* dst = wQ + (size_t)(g * 32 + kk8) * 768;
#pragma unroll
    for (int gate = 0; gate < 3; ++gate) {
      const float* src = whh + (size_t)(gate * 256 + tid) * HH + kk8 * 8;
      unsigned v0 = __half_as_ushort(__float2half(src[0]));
      unsigned v1 = __half_as_ushort(__float2half(src[1]));
      unsigned v2 = __half_as_ushort(__float2half(src[2]));
      unsigned v3 = __half_as_ushort(__float2half(src[3]));
      unsigned v4 = __half_as_ushort(__float2half(src[4]));
      unsigned v5 = __half_as_ushort(__float2half(src[5]));
      unsigned v6 = __half_as_ushort(__float2half(src[6]));
      unsigned v7 = __half_as_ushort(__float2half(src[7]));
      uint4 u;
      u.x = v0 | (v1 << 16);
      u.y = v2 | (v3 << 16);
      u.z = v4 | (v5 << 16);
      u.w = v6 | (v7 << 16);
      dst[gate * 256 + tid] = u;
    }
  } else if (bx < 1094) {                // x -> fp16 hi+lo (2 x 1048576)
    int base = (bx - 70) * 2048;
    for (int o = base + tid; o < base + 2048; o += 256) {
      float v = (o < 1048576) ? x_c[o] : x_p[o - 1048576];
      __half h = __float2half(v);
      xhi[o] = h;
      xlo[o] = __float2half(v - __half2float(h));
    }
  } else {                               // w_ih -> fp16 hi+lo (2 x 98304)
    int base = (bx - 1094) * 2048;
    for (int o = base + tid; o < base + 2048; o += 256) {
      float v = (o < 98304) ? wih_c[o] : wih_p[o - 98304];
      __half h = __float2half(v);
      whi[o] = h;
      wlo[o] = __float2half(v - __half2float(h));
    }
  }
}

// ---------------------------------------------------------------------------
// xp v2: LDS-tiled split-fp16 MFMA. Old version: every wave privately read
// its 16x128 A + 16x128 B (hi+lo) from global -> 49152 waves x 16 KB =
// ~790 MB => ~130-150 us memory-bound (suspected #2 kernel). Now: block =
// 128m x 96n tile, K=128 fully LDS-resident (A hi/lo + B hi/lo, rows padded
// to 136 f16 -> (68*lane)%32 start banks: conflict-free b128 phases).
// Traffic: A re-read 8x (n-panels) + B 64x (m-panels) = ~120 MB + 50 MB
// C-write => ~25-40 us. Fragment layout + chain order IDENTICAL to the
// harness-verified original (A[row=lm][k=q*8+e], B[col=lm][k], C[row=q*4+r]).
// grid (64, 8, 2) x 512.
// ---------------------------------------------------------------------------
__global__ __launch_bounds__(512) void xp_mfma(
    const __half* __restrict__ xhi, const __half* __restrict__ xlo,
    const __half* __restrict__ whi, const __half* __restrict__ wlo,
    fp bih_c, fp bih_p, float* __restrict__ xp)
{
  int g = blockIdx.z;
  int m0 = blockIdx.x * 128;
  int n0 = blockIdx.y * 96;
  const _Float16* xh = (const _Float16*)xhi + (size_t)g * 8192 * II;
  const _Float16* xl = (const _Float16*)xlo + (size_t)g * 8192 * II;
  const _Float16* wh = (const _Float16*)whi + (size_t)g * 768 * II;
  const _Float16* wl = (const _Float16*)wlo + (size_t)g * 768 * II;
  fp bih = g ? bih_p : bih_c;
  float* xpo = xp + (size_t)g * 8192 * 768;

  __shared__ _Float16 Ah[128][136];
  __shared__ _Float16 Al[128][136];
  __shared__ _Float16 Bh[96][136];
  __shared__ _Float16 Bl[96][136];

  int tid = threadIdx.x;
  // stage A: 128 rows x 16 f16x8 slots, hi+lo
  for (int i = tid; i < 2048; i += 512) {
    int r = i >> 4, s = i & 15;
    size_t go = (size_t)(m0 + r) * II + s * 8;
    *(f16x8*)&Ah[r][s * 8] = *(const f16x8*)(xh + go);
    *(f16x8*)&Al[r][s * 8] = *(const f16x8*)(xl + go);
  }
  // stage B: 96 rows x 16 slots, hi+lo
  for (int i = tid; i < 1536; i += 512) {
    int r = i >> 4, s = i & 15;
    size_t go = (size_t)(n0 + r) * II + s * 8;
    *(f16x8*)&Bh[r][s * 8] = *(const f16x8*)(wh + go);
    *(f16x8*)&Bl[r][s * 8] = *(const f16x8*)(wl + go);
  }
  __syncthreads();

  int wv = tid >> 6, l = tid & 63;
  int lm = l & 15, q = l >> 4;
  int mr = wv * 16 + lm;               // wave wv owns m-tile row wv

  f16x8 ah0 = *(const f16x8*)&Ah[mr][0 * 32 + q * 8];
  f16x8 ah1 = *(const f16x8*)&Ah[mr][1 * 32 + q * 8];
  f16x8 ah2 = *(const f16x8*)&Ah[mr][2 * 32 + q * 8];
  f16x8 ah3 = *(const f16x8*)&Ah[mr][3 * 32 + q * 8];
  f16x8 al0 = *(const f16x8*)&Al[mr][0 * 32 + q * 8];
  f16x8 al1 = *(const f16x8*)&Al[mr][1 * 32 + q * 8];
  f16x8 al2 = *(const f16x8*)&Al[mr][2 * 32 + q * 8];
  f16x8 al3 = *(const f16x8*)&Al[mr][3 * 32 + q * 8];

#pragma unroll
  for (int nj = 0; nj < 6; ++nj) {
    int nr = nj * 16 + lm;
    f32x4 acc = {0.f, 0.f, 0.f, 0.f};
    {
      f16x8 b = *(const f16x8*)&Bh[nr][0 * 32 + q * 8];
      f16x8 c = *(const f16x8*)&Bl[nr][0 * 32 + q * 8];
      acc = __builtin_amdgcn_mfma_f32_16x16x32_f16(ah0, b, acc, 0, 0, 0);
      acc = __builtin_amdgcn_mfma_f32_16x16x32_f16(al0, b, acc, 0, 0, 0);
      acc = __builtin_amdgcn_mfma_f32_16x16x32_f16(ah0, c, acc, 0, 0, 0);
    }
    {
      f16x8 b = *(const f16x8*)&Bh[nr][1 * 32 + q * 8];
      f16x8 c = *(const f16x8*)&Bl[nr][1 * 32 + q * 8];
      acc = __builtin_amdgcn_mfma_f32_16x16x32_f16(ah1, b, acc, 0, 0, 0);
      acc = __builtin_amdgcn_mfma_f32_16x16x32_f16(al1, b, acc, 0, 0, 0);
      acc = __builtin_amdgcn_mfma_f32_16x16x32_f16(ah1, c, acc, 0, 0, 0);
    }
    {
      f16x8 b = *(const f16x8*)&Bh[nr][2 * 32 + q * 8];
      f16x8 c = *(const f16x8*)&Bl[nr][2 * 32 + q * 8];
      acc = __builtin_amdgcn_mfma_f32_16x16x32_f16(ah2, b, acc, 0, 0, 0);
      acc = __builtin_amdgcn_mfma_f32_16x16x32_f16(al2, b, acc, 0, 0, 0);
      acc = __builtin_amdgcn_mfma_f32_16x16x32_f16(ah2, c, acc, 0, 0, 0);
    }
    {
      f16x8 b = *(const f16x8*)&Bh[nr][3 * 32 + q * 8];
      f16x8 c = *(const f16x8*)&Bl[nr][3 * 32 + q * 8];
      acc = __builtin_amdgcn_mfma_f32_16x16x32_f16(ah3, b, acc, 0, 0, 0);
      acc = __builtin_amdgcn_mfma_f32_16x16x32_f16(al3, b, acc, 0, 0, 0);
      acc = __builtin_amdgcn_mfma_f32_16x16x32_f16(ah3, c, acc, 0, 0, 0);
    }
    float bias = bih[n0 + nr];
#pragma unroll
    for (int r = 0; r < 4; ++r)
      xpo[(size_t)(m0 + wv * 16 + q * 4 + r) * 768 + n0 + nr] = acc[r] + bias;
  }
}

// ---------------------------------------------------------------------------
// fully-fused MPNN: one block per molecule (<=14 atoms).
// ---------------------------------------------------------------------------
__global__ __launch_bounds__(256) void mpnn_mol(
    const int* __restrict__ fingerprints, fp embed_fp, fp adj,
    const int* __restrict__ mstart, fp w_g0, fp b_g0, fp w_g1, fp b_g1,
    float* __restrict__ mol)
{
  int m = blockIdx.x, tid = threadIdx.x;
  int a0 = mstart[m], a1 = mstart[m + 1];
  int sz = a1 - a0;
  if (sz < 0) sz = 0;
  if (sz > 14) sz = 14;

  __shared__ float v[14][260];
  __shared__ float adjb[14][16];

#pragma unroll
  for (int i = 0; i < 14; ++i) {
    float val = 0.f;
    if (i < sz) {
      int f = fingerprints[a0 + i] & 1023;
      val = embed_fp[(size_t)f * HH + tid];
    }
    v[i][tid] = val;
  }
  if (tid < 224) {
    int i = tid >> 4, jj = tid & 15;
    float a = 0.f;
    if (i < sz && jj < sz)
      a = adj[(size_t)(a0 + i) * NATOMS_N + a0 + jj];
    adjb[i][jj] = a;
  }
  __syncthreads();

  float acc[14];
  for (int rd = 0; rd < 2; ++rd) {
    const float* wp0 = (rd ? w_g1 : w_g0) + tid;
#pragma unroll
    for (int i = 0; i < 14; ++i) acc[i] = 0.f;
    for (int k = 0; k < HH; k += 4) {
      float w0 = wp0[(size_t)k * HH];
      float w1 = wp0[(size_t)(k + 1) * HH];
      float w2 = wp0[(size_t)(k + 2) * HH];
      float w3 = wp0[(size_t)(k + 3) * HH];
#pragma unroll
      for (int i = 0; i < 14; ++i) {
        float4 vv = *(const float4*)&v[i][k];
        acc[i] = fmaf(vv.x, w0, acc[i]);
        acc[i] = fmaf(vv.y, w1, acc[i]);
        acc[i] = fmaf(vv.z, w2, acc[i]);
        acc[i] = fmaf(vv.w, w3, acc[i]);
      }
    }
    float bias = (rd ? b_g1 : b_g0)[tid];
    float hreg[14];
#pragma unroll
    for (int i = 0; i < 14; ++i) hreg[i] = fmaxf(acc[i] + bias, 0.f);
#pragma unroll
    for (int i = 0; i < 14; ++i) {
      float s = hreg[i];
#pragma unroll
      for (int jj = 0; jj < 14; ++jj) s = fmaf(adjb[i][jj], hreg[jj], s);
      acc[i] = s;
    }
    if (rd == 0) {
      __syncthreads();
#pragma unroll
      for (int i = 0; i < 14; ++i) v[i][tid] = acc[i];
      __syncthreads();
    }
  }
  float msum = 0.f;
#pragma unroll
  for (int i = 0; i < 14; ++i) if (i < sz) msum += acc[i];
  mol[(size_t)m * HH + tid] = msum;
}

// ---------------------------------------------------------------------------
// mpnn_emb^T[h][d] = sum_m avg[d][m] * mol[m][h]
// ---------------------------------------------------------------------------
__global__ __launch_bounds__(256) void mpnn_emb_k(
    fp avg, const float* __restrict__ mol, float* __restrict__ embT)
{
  int d = blockIdx.x, tid = threadIdx.x;
  float acc = 0.f;
  for (int m = 0; m < NMOL_N; ++m)
    acc += avg[d * NMOL_N + m] * mol[(size_t)m * HH + tid];
  embT[(size_t)tid * LBL + d] = acc;
}

// ---------------------------------------------------------------------------
// GRU v7 (dot2, k-split 4) — REVERTED from the MFMA experiments (v8-v10).
// v8-v10 all hit the unified-file register split: compiler caps arch VGPRs
// at 128 (accum_offset), the 192-reg persistent weight set spills to
// scratch, 48 serialized ~300-cyc reloads/step => 176-225 us. v7 streams
// fp16 weights from L2 at the per-CU ingress roofline (~121 GB/s/CU) =
// ~104 us measured-by-subtraction — the best known structure.
// ---------------------------------------------------------------------------
__global__ __launch_bounds__(1024) void gru_dot4(
    fp xp, const uint4* __restrict__ wQ, fp bhh_c, fp bhh_p,
    float* __restrict__ hcat, const int* __restrict__ idxv)
{
  int blk = blockIdx.x;
  int g = blk >> 7;
  int pair = blk & 127;
  int b1 = pair * 2, b2 = b1 + 1;
  int tid = threadIdx.x;
  int j = tid & 255;
  int kq = tid >> 8;                   // k-quarter 0..3

  __shared__ float hs[2][260];         // [batch][k]   fp32 state (proven)
  __shared__ unsigned hsh[2][132];     // [batch][k/2] packed fp16 mirror
  __shared__ float red[24][260];       // [kq*6 + batch*3 + gate][j]

  const uint4* wg = wQ + (size_t)(g * 32 + kq * 8) * 768 + j;
  fp bhh = g ? bhh_p : bhh_c;
  const float* xpg = xp + (size_t)g * 8192 * 768;

  if (tid < 256) { hs[0][j] = 0.f; hs[1][j] = 0.f; }
  if (tid < 128) hsh[0][tid] = 0u;
  else if (tid < 256) hsh[1][tid - 128] = 0u;
  float br = bhh[j], bz = bhh[j + 256], bn = bhh[j + 512];
  int bidx = kq & 1;                   // gate-phase batch (threads < 512)
  int myb = bidx ? b2 : b1;
  int myid = idxv[myb];
  __syncthreads();

  for (int t = 0; t < SS; ++t) {
    // dot phase: packed fp16 h (uint4 = 8 k-values) x packed fp16 weights
    const uint4* h1p = (const uint4*)&hsh[0][kq * 32];
    const uint4* h2p = (const uint4*)&hsh[1][kq * 32];
    float s1r = 0.f, s1z = 0.f, s1n = 0.f;
    float s2r = 0.f, s2z = 0.f, s2n = 0.f;
#pragma unroll
    for (int i = 0; i < 8; ++i) {
      uint4 H1 = h1p[i];
      uint4 H2 = h2p[i];
      const uint4* base = wg + (size_t)i * 768;
      uint4 ur = base[0];
      uint4 uz = base[256];
      uint4 un = base[512];
      s1r = dot2u(H1.x, ur.x, s1r); s1r = dot2u(H1.y, ur.y, s1r);
      s1r = dot2u(H1.z, ur.z, s1r); s1r = dot2u(H1.w, ur.w, s1r);
      s1z = dot2u(H1.x, uz.x, s1z); s1z = dot2u(H1.y, uz.y, s1z);
      s1z = dot2u(H1.z, uz.z, s1z); s1z = dot2u(H1.w, uz.w, s1z);
      s1n = dot2u(H1.x, un.x, s1n); s1n = dot2u(H1.y, un.y, s1n);
      s1n = dot2u(H1.z, un.z, s1n); s1n = dot2u(H1.w, un.w, s1n);
      s2r = dot2u(H2.x, ur.x, s2r); s2r = dot2u(H2.y, ur.y, s2r);
      s2r = dot2u(H2.z, ur.z, s2r); s2r = dot2u(H2.w, ur.w, s2r);
      s2z = dot2u(H2.x, uz.x, s2z); s2z = dot2u(H2.y, uz.y, s2z);
      s2z = dot2u(H2.z, uz.z, s2z); s2z = dot2u(H2.w, uz.w, s2z);
      s2n = dot2u(H2.x, un.x, s2n); s2n = dot2u(H2.y, un.y, s2n);
      s2n = dot2u(H2.z, un.z, s2n); s2n = dot2u(H2.w, un.w, s2n);
    }
    int rb = kq * 6;
    red[rb + 0][j] = s1r; red[rb + 1][j] = s1z; red[rb + 2][j] = s1n;
    red[rb + 3][j] = s2r; red[rb + 4][j] = s2z; red[rb + 5][j] = s2n;
    __syncthreads();                   // partials visible; all hsh reads done

    // gate phase: threads < 512, (bidx = batch-in-pair, j); fp32 state
    if (tid < 512) {
      int bb = bidx * 3;
      float sr = red[bb + 0][j] + red[bb + 6][j] + red[bb + 12][j] + red[bb + 18][j];
      float sz = red[bb + 1][j] + red[bb + 7][j] + red[bb + 13][j] + red[bb + 19][j];
      float sn = red[bb + 2][j] + red[bb + 8][j] + red[bb + 14][j] + red[bb + 20][j];
      const float* xrow = xpg + ((size_t)myb * SS + t) * 768;
      float r = sigm(xrow[j] + sr + br);
      float z = sigm(xrow[j + 256] + sz + bz);
      float n = tanhf(xrow[j + 512] + r * (sn + bn));
      float hnew = (1.f - z) * n + z * hs[bidx][j];
      hs[bidx][j] = hnew;
      if (t == myid) hcat[(size_t)myb * 512 + g * 256 + j] = fmaxf(hnew, 0.f);
    }
    __syncthreads();                   // hs update visible to pack phase

    // pack phase: 4-byte uint stores of fp16 pairs (no sub-dword writes)
    if (tid < 128) {
      unsigned lo16 = __half_as_ushort(__float2half(hs[0][2 * tid]));
      unsigned hi16 = __half_as_ushort(__float2half(hs[0][2 * tid + 1]));
      hsh[0][tid] = lo16 | (hi16 << 16);
    } else if (tid < 256) {
      int p = tid - 128;
      unsigned lo16 = __half_as_ushort(__float2half(hs[1][2 * p]));
      unsigned hi16 = __half_as_ushort(__float2half(hs[1][2 * p + 1]));
      hsh[1][p] = lo16 | (hi16 << 16);
    }
    __syncthreads();                   // hsh visible before next dot phase
  }
}

// ---------------------------------------------------------------------------
// fp32 GEMM for query: C[M,N] = A[M,K] @ W[K,N] + bias
// ---------------------------------------------------------------------------
__global__ __launch_bounds__(256) void gemm_f32(
    const float* __restrict__ A, fp W, fp bias, float* __restrict__ C,
    int M, int N, int K)
{
  int ntiles = N >> 4;
  int mt = blockIdx.x / ntiles, nt = blockIdx.x - mt * ntiles;
  int m0 = mt << 4, n0 = nt << 4;
  int tid = threadIdx.x;
  int ni = tid & 15, mi = tid >> 4;
  __shared__ float As[16][68];
  float acc = 0.f;
  for (int k0 = 0; k0 < K; k0 += 64) {
    __syncthreads();
    for (int i = tid; i < 1024; i += 256) {
      int r = i >> 6, kk = i & 63;
      As[r][kk] = A[(size_t)(m0 + r) * K + k0 + kk];
    }
    __syncthreads();
    const float* wp = W + (size_t)k0 * N + n0 + ni;
#pragma unroll 4
    for (int kk = 0; kk < 64; ++kk)
      acc = fmaf(As[mi][kk], wp[(size_t)kk * N], acc);
  }
  acc += bias[n0 + ni];
  C[(size_t)(m0 + mi) * N + n0 + ni] = acc;
}

// ---------------------------------------------------------------------------
// fused tail per batch row: match/x2/LN (mpnn_att) + bip/masked-linear + mul
// ---------------------------------------------------------------------------
__global__ __launch_bounds__(256) void tail_fused(
    const float* __restrict__ query, const float* __restrict__ embT,
    fp w_out, fp b_out, fp gamma, fp beta,
    fp w_bip, fp b_bip, const float* __restrict__ mw,
    float* __restrict__ out)
{
  int b = blockIdx.x, tid = threadIdx.x;
  __shared__ float q[HH];
  __shared__ float mrow[LBL];
  __shared__ float bips[NSUBS];
  __shared__ float red[256];
  q[tid] = query[(size_t)b * HH + tid];
  __syncthreads();
  if (tid < LBL) {
    float acc = 0.f;
    for (int k = 0; k < HH; ++k) acc += q[k] * embT[(size_t)k * LBL + tid];
    mrow[tid] = sigm(acc);
  }
  for (int s = tid; s < NSUBS; s += 256) {
    float acc = b_bip[s];
    for (int k = 0; k < HH; ++k) acc += q[k] * w_bip[(size_t)k * NSUBS + s];
    bips[s] = acc;
  }
  __syncthreads();
  float x2 = 0.f;
  if (tid < LBL) {
    float acc = b_out[tid] + mrow[tid];
    for (int jj = 0; jj < LBL; ++jj) acc += mrow[jj] * w_out[jj * LBL + tid];
    x2 = acc;
  }
  red[tid] = (tid < LBL) ? x2 : 0.f;
  __syncthreads();
  for (int s = 128; s > 0; s >>= 1) {
    if (tid < s) red[tid] += red[tid + s];
    __syncthreads();
  }
  float mu = red[0] / (float)LBL;
  __syncthreads();
  float dv = (tid < LBL) ? (x2 - mu) : 0.f;
  red[tid] = dv * dv;
  __syncthreads();
  for (int s = 128; s > 0; s >>= 1) {
    if (tid < s) red[tid] += red[tid + s];
    __syncthreads();
  }
  float var = red[0] / (float)LBL;
  if (tid < LBL) {
    float matt = (x2 - mu) * rsqrtf(var + 1e-5f) * gamma[tid] + beta[tid];
    float acc = 0.f;
    for (int s = 0; s < NSUBS; ++s) acc += bips[s] * mw[(size_t)s * LBL + tid];
    out[(size_t)b * LBL + tid] = acc * matt;
  }
}

// ---------------------------------------------------------------------------
extern "C" void kernel_launch(void* const* d_in, const int* in_sizes, int n_in,
                              void* d_out, int out_size, void* d_ws, size_t ws_size,
                              hipStream_t stream)
{
  fp x_c   = (fp)d_in[0];
  fp x_p   = (fp)d_in[1];
  const int* mask = (const int*)d_in[2];
  fp wih_c = (fp)d_in[3];
  fp whh_c = (fp)d_in[4];
  fp bih_c = (fp)d_in[5];
  fp bhh_c = (fp)d_in[6];
  fp wih_p = (fp)d_in[7];
  fp whh_p = (fp)d_in[8];
  fp bih_p = (fp)d_in[9];
  fp bhh_p = (fp)d_in[10];
  fp w_query = (fp)d_in[11];
  fp b_query = (fp)d_in[12];
  fp w_bip = (fp)d_in[13];
  fp b_bip = (fp)d_in[14];
  fp w_masklin = (fp)d_in[15];
  fp ddi = (fp)d_in[16];
  fp embed_fp = (fp)d_in[17];
  const int* fingerprints = (const int*)d_in[18];
  fp adj = (fp)d_in[19];
  const int* seg = (const int*)d_in[20];
  fp w_g0 = (fp)d_in[21];
  fp b_g0 = (fp)d_in[22];
  fp w_g1 = (fp)d_in[23];
  fp b_g1 = (fp)d_in[24];
  fp avg = (fp)d_in[25];
  fp w_out = (fp)d_in[26];
  fp b_out = (fp)d_in[27];
  fp gamma = (fp)d_in[28];
  fp beta = (fp)d_in[29];
  float* out = (float*)d_out;

  char* w = (char*)d_ws;
  size_t off = 0;
  auto alloc = [&](size_t bytes) -> void* {
    void* p = w + off;
    off = (off + bytes + 255) & ~(size_t)255;
    return p;
  };

  float* xp   = (float*)alloc((size_t)2 * 8192 * 768 * 4);    // 50.3 MB
  __half* xhi = (__half*)alloc((size_t)2 * 8192 * 128 * 2);   // 4.2 MB
  __half* xlo = (__half*)alloc((size_t)2 * 8192 * 128 * 2);   // 4.2 MB
  __half* whi = (__half*)alloc((size_t)2 * 768 * 128 * 2);    // 0.4 MB
  __half* wlo = (__half*)alloc((size_t)2 * 768 * 128 * 2);    // 0.4 MB
  uint4* wQ   = (uint4*)alloc((size_t)2 * 32 * 768 * 16);     // 786 KB
  float* mol  = (float*)alloc((size_t)NMOL_N * HH * 4);
  float* embT = (float*)alloc((size_t)HH * LBL * 4);
  float* hcat = (float*)alloc((size_t)BB * 2 * HH * 4);
  float* query = (float*)alloc((size_t)BB * HH * 4);
  float* mw   = (float*)alloc((size_t)NSUBS * LBL * 4);
  int* idxv   = (int*)alloc(256 * 4);
  int* mstart = (int*)alloc((NMOL_N + 1) * 4);

  prep_kernel<<<1190, 256, 0, stream>>>(mask, idxv, seg, mstart, w_masklin,
                                        ddi, mw, whh_c, whh_p, wQ,
                                        x_c, x_p, xhi, xlo,
                                        wih_c, wih_p, whi, wlo);

  xp_mfma<<<dim3(64, 8, 2), 512, 0, stream>>>(xhi, xlo, whi, wlo,
                                              bih_c, bih_p, xp);

  mpnn_mol<<<NMOL_N, 256, 0, stream>>>(fingerprints, embed_fp, adj, mstart,
                                       w_g0, b_g0, w_g1, b_g1, mol);
  mpnn_emb_k<<<LBL, 256, 0, stream>>>(avg, mol, embT);

  gru_dot4<<<256, 1024, 0, stream>>>(xp, wQ, bhh_c, bhh_p, hcat, idxv);

  gemm_f32<<<256, 256, 0, stream>>>(hcat, w_query, b_query, query, BB, HH, 2 * HH);
  tail_fused<<<BB, 256, 0, stream>>>(query, embT, w_out, b_out, gamma, beta,
                                     w_bip, b_bip, mw, out);
}

// Round 14
// 655.743 us; speedup vs baseline: 1.4173x; 1.1268x over previous
//
#include <hip/hip_runtime.h>
#include <hip/hip_bf16.h>
#include <hip/hip_fp16.h>

#define BB 256
#define SS 32
#define II 128
#define HH 256
#define LBL 200
#define NSUBS 491
#define NATOMS_N 8000
#define NMOL_N 600

typedef const float* fp;
typedef __attribute__((ext_vector_type(2))) _Float16 h2t;
typedef __attribute__((ext_vector_type(8))) _Float16 f16x8;
typedef __attribute__((ext_vector_type(4))) float f32x4;

__device__ __forceinline__ float sigm(float x) { return 1.f / (1.f + expf(-x)); }
__device__ __forceinline__ float hlo(unsigned u) {
  return __half2float(__ushort_as_half((unsigned short)(u & 0xffffu)));
}
__device__ __forceinline__ float hhi(unsigned u) {
  return __half2float(__ushort_as_half((unsigned short)(u >> 16)));
}

#if __has_builtin(__builtin_amdgcn_fdot2)
__device__ __forceinline__ float dot2u(unsigned ha, unsigned wa, float acc) {
  return __builtin_amdgcn_fdot2(__builtin_bit_cast(h2t, ha),
                                __builtin_bit_cast(h2t, wa), acc, false);
}
#else
__device__ __forceinline__ float dot2u(unsigned ha, unsigned wa, float acc) {
  acc = fmaf(hlo(ha), hlo(wa), acc);
  return fmaf(hhi(ha), hhi(wa), acc);
}
#endif

// ---------------------------------------------------------------------------
// prep (1190 blocks): idxv, mstart, masked w_masklin, fp16 uint4-packed GRU
// weights wQ (for gru_dot4), and SPLIT-fp16 conversions of x and w_ih.
// ---------------------------------------------------------------------------
__global__ __launch_bounds__(256) void prep_kernel(
    const int* __restrict__ mask, int* __restrict__ idxv,
    const int* __restrict__ seg, int* __restrict__ mstart,
    fp w_masklin, fp ddi, float* __restrict__ mw,
    fp whh_c, fp whh_p, uint4* __restrict__ wQ,
    fp x_c, fp x_p, __half* __restrict__ xhi, __half* __restrict__ xlo,
    fp wih_c, fp wih_p, __half* __restrict__ whi, __half* __restrict__ wlo)
{
  int bx = blockIdx.x, tid = threadIdx.x;
  if (bx == 0) {                         // idx[b] = clamp(sum(mask[b,:]) - 1)
    int s = 0;
    const int* mrow = mask + tid * SS;
    for (int t = 0; t < SS; ++t) s += mrow[t];
    s -= 1;
    if (s < 0) s = 0;
    if (s > SS - 1) s = SS - 1;
    idxv[tid] = s;
  } else if (bx == 1) {                  // mstart[m] = lower_bound(seg, m)
    for (int m = tid; m <= NMOL_N; m += 256) {
      if (m == NMOL_N) { mstart[m] = NATOMS_N; continue; }
      int lo = 0, hi = NATOMS_N;
      while (lo < hi) {
        int mid = (lo + hi) >> 1;
        if (seg[mid] < m) lo = mid + 1; else hi = mid;
      }
      mstart[m] = lo;
    }
  } else if (bx < 6) {                   // mw[s][l] = w_masklin[s][l]*ddi[l][s]
    for (int o = (bx - 2) * 256 + tid; o < NSUBS * LBL; o += 4 * 256) {
      int s = o / LBL, l = o - s * LBL;
      mw[o] = w_masklin[o] * ddi[l * NSUBS + s];
    }
  } else if (bx < 70) {                  // weight pack: one (g, kk8) per block
    int lin = bx - 6;                    // 0..63
    int g = lin >> 5;
    int kk8 = lin & 31;
    fp whh = g ? whh_p : whh_c;
    uint4* dst = wQ + (size_t)(g * 32 + kk8) * 768;
#pragma unroll
    for (int gate = 0; gate < 3; ++gate) {
      const float* src = whh + (size_t)(gate * 256 + tid) * HH + kk8 * 8;
      unsigned v0 = __half_as_ushort(__float2half(src[0]));
      unsigned v1 = __half_as_ushort(__float2half(src[1]));
      unsigned v2 = __half_as_ushort(__float2half(src[2]));
      unsigned v3 = __half_as_ushort(__float2half(src[3]));
      unsigned v4 = __half_as_ushort(__float2half(src[4]));
      unsigned v5 = __half_as_ushort(__float2half(src[5]));
      unsigned v6 = __half_as_ushort(__float2half(src[6]));
      unsigned v7 = __half_as_ushort(__float2half(src[7]));
      uint4 u;
      u.x = v0 | (v1 << 16);
      u.y = v2 | (v3 << 16);
      u.z = v4 | (v5 << 16);
      u.w = v6 | (v7 << 16);
      dst[gate * 256 + tid] = u;
    }
  } else if (bx < 1094) {                // x -> fp16 hi+lo (2 x 1048576)
    int base = (bx - 70) * 2048;
    for (int o = base + tid; o < base + 2048; o += 256) {
      float v = (o < 1048576) ? x_c[o] : x_p[o - 1048576];
      __half h = __float2half(v);
      xhi[o] = h;
      xlo[o] = __float2half(v - __half2float(h));
    }
  } else {                               // w_ih -> fp16 hi+lo (2 x 98304)
    int base = (bx - 1094) * 2048;
    for (int o = base + tid; o < base + 2048; o += 256) {
      float v = (o < 98304) ? wih_c[o] : wih_p[o - 98304];
      __half h = __float2half(v);
      whi[o] = h;
      wlo[o] = __float2half(v - __half2float(h));
    }
  }
}

// ---------------------------------------------------------------------------
// xp v2: LDS-tiled split-fp16 MFMA (verified r12: ~71 us saved vs private
// per-wave reads). grid (64, 8, 2) x 512.
// ---------------------------------------------------------------------------
__global__ __launch_bounds__(512) void xp_mfma(
    const __half* __restrict__ xhi, const __half* __restrict__ xlo,
    const __half* __restrict__ whi, const __half* __restrict__ wlo,
    fp bih_c, fp bih_p, float* __restrict__ xp)
{
  int g = blockIdx.z;
  int m0 = blockIdx.x * 128;
  int n0 = blockIdx.y * 96;
  const _Float16* xh = (const _Float16*)xhi + (size_t)g * 8192 * II;
  const _Float16* xl = (const _Float16*)xlo + (size_t)g * 8192 * II;
  const _Float16* wh = (const _Float16*)whi + (size_t)g * 768 * II;
  const _Float16* wl = (const _Float16*)wlo + (size_t)g * 768 * II;
  fp bih = g ? bih_p : bih_c;
  float* xpo = xp + (size_t)g * 8192 * 768;

  __shared__ _Float16 Ah[128][136];
  __shared__ _Float16 Al[128][136];
  __shared__ _Float16 Bh[96][136];
  __shared__ _Float16 Bl[96][136];

  int tid = threadIdx.x;
  for (int i = tid; i < 2048; i += 512) {
    int r = i >> 4, s = i & 15;
    size_t go = (size_t)(m0 + r) * II + s * 8;
    *(f16x8*)&Ah[r][s * 8] = *(const f16x8*)(xh + go);
    *(f16x8*)&Al[r][s * 8] = *(const f16x8*)(xl + go);
  }
  for (int i = tid; i < 1536; i += 512) {
    int r = i >> 4, s = i & 15;
    size_t go = (size_t)(n0 + r) * II + s * 8;
    *(f16x8*)&Bh[r][s * 8] = *(const f16x8*)(wh + go);
    *(f16x8*)&Bl[r][s * 8] = *(const f16x8*)(wl + go);
  }
  __syncthreads();

  int wv = tid >> 6, l = tid & 63;
  int lm = l & 15, q = l >> 4;
  int mr = wv * 16 + lm;

  f16x8 ah0 = *(const f16x8*)&Ah[mr][0 * 32 + q * 8];
  f16x8 ah1 = *(const f16x8*)&Ah[mr][1 * 32 + q * 8];
  f16x8 ah2 = *(const f16x8*)&Ah[mr][2 * 32 + q * 8];
  f16x8 ah3 = *(const f16x8*)&Ah[mr][3 * 32 + q * 8];
  f16x8 al0 = *(const f16x8*)&Al[mr][0 * 32 + q * 8];
  f16x8 al1 = *(const f16x8*)&Al[mr][1 * 32 + q * 8];
  f16x8 al2 = *(const f16x8*)&Al[mr][2 * 32 + q * 8];
  f16x8 al3 = *(const f16x8*)&Al[mr][3 * 32 + q * 8];

#pragma unroll
  for (int nj = 0; nj < 6; ++nj) {
    int nr = nj * 16 + lm;
    f32x4 acc = {0.f, 0.f, 0.f, 0.f};
    {
      f16x8 b = *(const f16x8*)&Bh[nr][0 * 32 + q * 8];
      f16x8 c = *(const f16x8*)&Bl[nr][0 * 32 + q * 8];
      acc = __builtin_amdgcn_mfma_f32_16x16x32_f16(ah0, b, acc, 0, 0, 0);
      acc = __builtin_amdgcn_mfma_f32_16x16x32_f16(al0, b, acc, 0, 0, 0);
      acc = __builtin_amdgcn_mfma_f32_16x16x32_f16(ah0, c, acc, 0, 0, 0);
    }
    {
      f16x8 b = *(const f16x8*)&Bh[nr][1 * 32 + q * 8];
      f16x8 c = *(const f16x8*)&Bl[nr][1 * 32 + q * 8];
      acc = __builtin_amdgcn_mfma_f32_16x16x32_f16(ah1, b, acc, 0, 0, 0);
      acc = __builtin_amdgcn_mfma_f32_16x16x32_f16(al1, b, acc, 0, 0, 0);
      acc = __builtin_amdgcn_mfma_f32_16x16x32_f16(ah1, c, acc, 0, 0, 0);
    }
    {
      f16x8 b = *(const f16x8*)&Bh[nr][2 * 32 + q * 8];
      f16x8 c = *(const f16x8*)&Bl[nr][2 * 32 + q * 8];
      acc = __builtin_amdgcn_mfma_f32_16x16x32_f16(ah2, b, acc, 0, 0, 0);
      acc = __builtin_amdgcn_mfma_f32_16x16x32_f16(al2, b, acc, 0, 0, 0);
      acc = __builtin_amdgcn_mfma_f32_16x16x32_f16(ah2, c, acc, 0, 0, 0);
    }
    {
      f16x8 b = *(const f16x8*)&Bh[nr][3 * 32 + q * 8];
      f16x8 c = *(const f16x8*)&Bl[nr][3 * 32 + q * 8];
      acc = __builtin_amdgcn_mfma_f32_16x16x32_f16(ah3, b, acc, 0, 0, 0);
      acc = __builtin_amdgcn_mfma_f32_16x16x32_f16(al3, b, acc, 0, 0, 0);
      acc = __builtin_amdgcn_mfma_f32_16x16x32_f16(ah3, c, acc, 0, 0, 0);
    }
    float bias = bih[n0 + nr];
#pragma unroll
    for (int r = 0; r < 4; ++r)
      xpo[(size_t)(m0 + wv * 16 + q * 4 + r) * 768 + n0 + nr] = acc[r] + bias;
  }
}

// ---------------------------------------------------------------------------
// fully-fused MPNN: one block per molecule. k-loop widened 4->8 independent
// weight loads in flight (latency-bound fix: stride-1KB L2 reads exposed).
// ---------------------------------------------------------------------------
__global__ __launch_bounds__(256) void mpnn_mol(
    const int* __restrict__ fingerprints, fp embed_fp, fp adj,
    const int* __restrict__ mstart, fp w_g0, fp b_g0, fp w_g1, fp b_g1,
    float* __restrict__ mol)
{
  int m = blockIdx.x, tid = threadIdx.x;
  int a0 = mstart[m], a1 = mstart[m + 1];
  int sz = a1 - a0;
  if (sz < 0) sz = 0;
  if (sz > 14) sz = 14;

  __shared__ float v[14][260];
  __shared__ float adjb[14][16];

#pragma unroll
  for (int i = 0; i < 14; ++i) {
    float val = 0.f;
    if (i < sz) {
      int f = fingerprints[a0 + i] & 1023;
      val = embed_fp[(size_t)f * HH + tid];
    }
    v[i][tid] = val;
  }
  if (tid < 224) {
    int i = tid >> 4, jj = tid & 15;
    float a = 0.f;
    if (i < sz && jj < sz)
      a = adj[(size_t)(a0 + i) * NATOMS_N + a0 + jj];
    adjb[i][jj] = a;
  }
  __syncthreads();

  float acc[14];
  for (int rd = 0; rd < 2; ++rd) {
    const float* wp0 = (rd ? w_g1 : w_g0) + tid;
#pragma unroll
    for (int i = 0; i < 14; ++i) acc[i] = 0.f;
    for (int k = 0; k < HH; k += 8) {
      float w0 = wp0[(size_t)k * HH];
      float w1 = wp0[(size_t)(k + 1) * HH];
      float w2 = wp0[(size_t)(k + 2) * HH];
      float w3 = wp0[(size_t)(k + 3) * HH];
      float w4 = wp0[(size_t)(k + 4) * HH];
      float w5 = wp0[(size_t)(k + 5) * HH];
      float w6 = wp0[(size_t)(k + 6) * HH];
      float w7 = wp0[(size_t)(k + 7) * HH];
#pragma unroll
      for (int i = 0; i < 14; ++i) {
        float4 va = *(const float4*)&v[i][k];
        float4 vb = *(const float4*)&v[i][k + 4];
        acc[i] = fmaf(va.x, w0, acc[i]);
        acc[i] = fmaf(va.y, w1, acc[i]);
        acc[i] = fmaf(va.z, w2, acc[i]);
        acc[i] = fmaf(va.w, w3, acc[i]);
        acc[i] = fmaf(vb.x, w4, acc[i]);
        acc[i] = fmaf(vb.y, w5, acc[i]);
        acc[i] = fmaf(vb.z, w6, acc[i]);
        acc[i] = fmaf(vb.w, w7, acc[i]);
      }
    }
    float bias = (rd ? b_g1 : b_g0)[tid];
    float hreg[14];
#pragma unroll
    for (int i = 0; i < 14; ++i) hreg[i] = fmaxf(acc[i] + bias, 0.f);
#pragma unroll
    for (int i = 0; i < 14; ++i) {
      float s = hreg[i];
#pragma unroll
      for (int jj = 0; jj < 14; ++jj) s = fmaf(adjb[i][jj], hreg[jj], s);
      acc[i] = s;
    }
    if (rd == 0) {
      __syncthreads();
#pragma unroll
      for (int i = 0; i < 14; ++i) v[i][tid] = acc[i];
      __syncthreads();
    }
  }
  float msum = 0.f;
#pragma unroll
  for (int i = 0; i < 14; ++i) if (i < sz) msum += acc[i];
  mol[(size_t)m * HH + tid] = msum;
}

// ---------------------------------------------------------------------------
// mpnn_emb^T[h][d] = sum_m avg[d][m]*mol[m][h]. 600 sequential dependent
// iterations at 200 blocks was latency-bound; 4 independent chains.
// ---------------------------------------------------------------------------
__global__ __launch_bounds__(256) void mpnn_emb_k(
    fp avg, const float* __restrict__ mol, float* __restrict__ embT)
{
  int d = blockIdx.x, tid = threadIdx.x;
  const float* ar = avg + (size_t)d * NMOL_N;
  float a0 = 0.f, a1 = 0.f, a2 = 0.f, a3 = 0.f;
  for (int m = 0; m < NMOL_N; m += 4) {
    a0 = fmaf(ar[m],     mol[(size_t)m * HH + tid],       a0);
    a1 = fmaf(ar[m + 1], mol[(size_t)(m + 1) * HH + tid], a1);
    a2 = fmaf(ar[m + 2], mol[(size_t)(m + 2) * HH + tid], a2);
    a3 = fmaf(ar[m + 3], mol[(size_t)(m + 3) * HH + tid], a3);
  }
  embT[(size_t)tid * LBL + d] = (a0 + a1) + (a2 + a3);
}

// ---------------------------------------------------------------------------
// GRU v7 (dot2, k-split 4) — verified best (~104 us, per-CU L2-ingress
// roofline). Unchanged.
// ---------------------------------------------------------------------------
__global__ __launch_bounds__(1024) void gru_dot4(
    fp xp, const uint4* __restrict__ wQ, fp bhh_c, fp bhh_p,
    float* __restrict__ hcat, const int* __restrict__ idxv)
{
  int blk = blockIdx.x;
  int g = blk >> 7;
  int pair = blk & 127;
  int b1 = pair * 2, b2 = b1 + 1;
  int tid = threadIdx.x;
  int j = tid & 255;
  int kq = tid >> 8;                   // k-quarter 0..3

  __shared__ float hs[2][260];         // [batch][k]   fp32 state (proven)
  __shared__ unsigned hsh[2][132];     // [batch][k/2] packed fp16 mirror
  __shared__ float red[24][260];       // [kq*6 + batch*3 + gate][j]

  const uint4* wg = wQ + (size_t)(g * 32 + kq * 8) * 768 + j;
  fp bhh = g ? bhh_p : bhh_c;
  const float* xpg = xp + (size_t)g * 8192 * 768;

  if (tid < 256) { hs[0][j] = 0.f; hs[1][j] = 0.f; }
  if (tid < 128) hsh[0][tid] = 0u;
  else if (tid < 256) hsh[1][tid - 128] = 0u;
  float br = bhh[j], bz = bhh[j + 256], bn = bhh[j + 512];
  int bidx = kq & 1;                   // gate-phase batch (threads < 512)
  int myb = bidx ? b2 : b1;
  int myid = idxv[myb];
  __syncthreads();

  for (int t = 0; t < SS; ++t) {
    // dot phase: packed fp16 h (uint4 = 8 k-values) x packed fp16 weights
    const uint4* h1p = (const uint4*)&hsh[0][kq * 32];
    const uint4* h2p = (const uint4*)&hsh[1][kq * 32];
    float s1r = 0.f, s1z = 0.f, s1n = 0.f;
    float s2r = 0.f, s2z = 0.f, s2n = 0.f;
#pragma unroll
    for (int i = 0; i < 8; ++i) {
      uint4 H1 = h1p[i];
      uint4 H2 = h2p[i];
      const uint4* base = wg + (size_t)i * 768;
      uint4 ur = base[0];
      uint4 uz = base[256];
      uint4 un = base[512];
      s1r = dot2u(H1.x, ur.x, s1r); s1r = dot2u(H1.y, ur.y, s1r);
      s1r = dot2u(H1.z, ur.z, s1r); s1r = dot2u(H1.w, ur.w, s1r);
      s1z = dot2u(H1.x, uz.x, s1z); s1z = dot2u(H1.y, uz.y, s1z);
      s1z = dot2u(H1.z, uz.z, s1z); s1z = dot2u(H1.w, uz.w, s1z);
      s1n = dot2u(H1.x, un.x, s1n); s1n = dot2u(H1.y, un.y, s1n);
      s1n = dot2u(H1.z, un.z, s1n); s1n = dot2u(H1.w, un.w, s1n);
      s2r = dot2u(H2.x, ur.x, s2r); s2r = dot2u(H2.y, ur.y, s2r);
      s2r = dot2u(H2.z, ur.z, s2r); s2r = dot2u(H2.w, ur.w, s2r);
      s2z = dot2u(H2.x, uz.x, s2z); s2z = dot2u(H2.y, uz.y, s2z);
      s2z = dot2u(H2.z, uz.z, s2z); s2z = dot2u(H2.w, uz.w, s2z);
      s2n = dot2u(H2.x, un.x, s2n); s2n = dot2u(H2.y, un.y, s2n);
      s2n = dot2u(H2.z, un.z, s2n); s2n = dot2u(H2.w, un.w, s2n);
    }
    int rb = kq * 6;
    red[rb + 0][j] = s1r; red[rb + 1][j] = s1z; red[rb + 2][j] = s1n;
    red[rb + 3][j] = s2r; red[rb + 4][j] = s2z; red[rb + 5][j] = s2n;
    __syncthreads();                   // partials visible; all hsh reads done

    // gate phase: threads < 512, (bidx = batch-in-pair, j); fp32 state
    if (tid < 512) {
      int bb = bidx * 3;
      float sr = red[bb + 0][j] + red[bb + 6][j] + red[bb + 12][j] + red[bb + 18][j];
      float sz = red[bb + 1][j] + red[bb + 7][j] + red[bb + 13][j] + red[bb + 19][j];
      float sn = red[bb + 2][j] + red[bb + 8][j] + red[bb + 14][j] + red[bb + 20][j];
      const float* xrow = xpg + ((size_t)myb * SS + t) * 768;
      float r = sigm(xrow[j] + sr + br);
      float z = sigm(xrow[j + 256] + sz + bz);
      float n = tanhf(xrow[j + 512] + r * (sn + bn));
      float hnew = (1.f - z) * n + z * hs[bidx][j];
      hs[bidx][j] = hnew;
      if (t == myid) hcat[(size_t)myb * 512 + g * 256 + j] = fmaxf(hnew, 0.f);
    }
    __syncthreads();                   // hs update visible to pack phase

    // pack phase: 4-byte uint stores of fp16 pairs (no sub-dword writes)
    if (tid < 128) {
      unsigned lo16 = __half_as_ushort(__float2half(hs[0][2 * tid]));
      unsigned hi16 = __half_as_ushort(__float2half(hs[0][2 * tid + 1]));
      hsh[0][tid] = lo16 | (hi16 << 16);
    } else if (tid < 256) {
      int p = tid - 128;
      unsigned lo16 = __half_as_ushort(__float2half(hs[1][2 * p]));
      unsigned hi16 = __half_as_ushort(__float2half(hs[1][2 * p + 1]));
      hsh[1][p] = lo16 | (hi16 << 16);
    }
    __syncthreads();                   // hsh visible before next dot phase
  }
}

// ---------------------------------------------------------------------------
// fp32 GEMM for query: 4 independent acc chains (stride-1KB W reads were
// serialized on one acc).
// ---------------------------------------------------------------------------
__global__ __launch_bounds__(256) void gemm_f32(
    const float* __restrict__ A, fp W, fp bias, float* __restrict__ C,
    int M, int N, int K)
{
  int ntiles = N >> 4;
  int mt = blockIdx.x / ntiles, nt = blockIdx.x - mt * ntiles;
  int m0 = mt << 4, n0 = nt << 4;
  int tid = threadIdx.x;
  int ni = tid & 15, mi = tid >> 4;
  __shared__ float As[16][68];
  float a0 = 0.f, a1 = 0.f, a2 = 0.f, a3 = 0.f;
  for (int k0 = 0; k0 < K; k0 += 64) {
    __syncthreads();
    for (int i = tid; i < 1024; i += 256) {
      int r = i >> 6, kk = i & 63;
      As[r][kk] = A[(size_t)(m0 + r) * K + k0 + kk];
    }
    __syncthreads();
    const float* wp = W + (size_t)k0 * N + n0 + ni;
#pragma unroll 4
    for (int kk = 0; kk < 64; kk += 4) {
      a0 = fmaf(As[mi][kk],     wp[(size_t)kk * N],       a0);
      a1 = fmaf(As[mi][kk + 1], wp[(size_t)(kk + 1) * N], a1);
      a2 = fmaf(As[mi][kk + 2], wp[(size_t)(kk + 2) * N], a2);
      a3 = fmaf(As[mi][kk + 3], wp[(size_t)(kk + 3) * N], a3);
    }
  }
  float acc = (a0 + a1) + (a2 + a3) + bias[n0 + ni];
  C[(size_t)(m0 + mi) * N + n0 + ni] = acc;
}

// ---------------------------------------------------------------------------
// fused tail: all four serial k-loops get 4 independent acc chains
// (strided global reads at 800B-2KB were latency-serialized).
// ---------------------------------------------------------------------------
__global__ __launch_bounds__(256) void tail_fused(
    const float* __restrict__ query, const float* __restrict__ embT,
    fp w_out, fp b_out, fp gamma, fp beta,
    fp w_bip, fp b_bip, const float* __restrict__ mw,
    float* __restrict__ out)
{
  int b = blockIdx.x, tid = threadIdx.x;
  __shared__ float q[HH];
  __shared__ float mrow[LBL];
  __shared__ float bips[NSUBS];
  __shared__ float red[256];
  q[tid] = query[(size_t)b * HH + tid];
  __syncthreads();
  if (tid < LBL) {
    float t0 = 0.f, t1 = 0.f, t2 = 0.f, t3 = 0.f;
    for (int k = 0; k < HH; k += 4) {
      t0 = fmaf(q[k],     embT[(size_t)k * LBL + tid],       t0);
      t1 = fmaf(q[k + 1], embT[(size_t)(k + 1) * LBL + tid], t1);
      t2 = fmaf(q[k + 2], embT[(size_t)(k + 2) * LBL + tid], t2);
      t3 = fmaf(q[k + 3], embT[(size_t)(k + 3) * LBL + tid], t3);
    }
    mrow[tid] = sigm((t0 + t1) + (t2 + t3));
  }
  for (int s = tid; s < NSUBS; s += 256) {
    float t0 = b_bip[s], t1 = 0.f, t2 = 0.f, t3 = 0.f;
    for (int k = 0; k < HH; k += 4) {
      t0 = fmaf(q[k],     w_bip[(size_t)k * NSUBS + s],       t0);
      t1 = fmaf(q[k + 1], w_bip[(size_t)(k + 1) * NSUBS + s], t1);
      t2 = fmaf(q[k + 2], w_bip[(size_t)(k + 2) * NSUBS + s], t2);
      t3 = fmaf(q[k + 3], w_bip[(size_t)(k + 3) * NSUBS + s], t3);
    }
    bips[s] = (t0 + t1) + (t2 + t3);
  }
  __syncthreads();
  float x2 = 0.f;
  if (tid < LBL) {
    float t0 = b_out[tid] + mrow[tid], t1 = 0.f, t2 = 0.f, t3 = 0.f;
    for (int jj = 0; jj < LBL; jj += 4) {
      t0 = fmaf(mrow[jj],     w_out[(jj) * LBL + tid],     t0);
      t1 = fmaf(mrow[jj + 1], w_out[(jj + 1) * LBL + tid], t1);
      t2 = fmaf(mrow[jj + 2], w_out[(jj + 2) * LBL + tid], t2);
      t3 = fmaf(mrow[jj + 3], w_out[(jj + 3) * LBL + tid], t3);
    }
    x2 = (t0 + t1) + (t2 + t3);
  }
  red[tid] = (tid < LBL) ? x2 : 0.f;
  __syncthreads();
  for (int s = 128; s > 0; s >>= 1) {
    if (tid < s) red[tid] += red[tid + s];
    __syncthreads();
  }
  float mu = red[0] / (float)LBL;
  __syncthreads();
  float dv = (tid < LBL) ? (x2 - mu) : 0.f;
  red[tid] = dv * dv;
  __syncthreads();
  for (int s = 128; s > 0; s >>= 1) {
    if (tid < s) red[tid] += red[tid + s];
    __syncthreads();
  }
  float var = red[0] / (float)LBL;
  if (tid < LBL) {
    float matt = (x2 - mu) * rsqrtf(var + 1e-5f) * gamma[tid] + beta[tid];
    float t0 = 0.f, t1 = 0.f, t2 = 0.f, t3 = 0.f;
    int s = 0;
    for (; s + 3 < NSUBS; s += 4) {
      t0 = fmaf(bips[s],     mw[(size_t)s * LBL + tid],       t0);
      t1 = fmaf(bips[s + 1], mw[(size_t)(s + 1) * LBL + tid], t1);
      t2 = fmaf(bips[s + 2], mw[(size_t)(s + 2) * LBL + tid], t2);
      t3 = fmaf(bips[s + 3], mw[(size_t)(s + 3) * LBL + tid], t3);
    }
    for (; s < NSUBS; ++s) t0 = fmaf(bips[s], mw[(size_t)s * LBL + tid], t0);
    out[(size_t)b * LBL + tid] = ((t0 + t1) + (t2 + t3)) * matt;
  }
}

// ---------------------------------------------------------------------------
extern "C" void kernel_launch(void* const* d_in, const int* in_sizes, int n_in,
                              void* d_out, int out_size, void* d_ws, size_t ws_size,
                              hipStream_t stream)
{
  fp x_c   = (fp)d_in[0];
  fp x_p   = (fp)d_in[1];
  const int* mask = (const int*)d_in[2];
  fp wih_c = (fp)d_in[3];
  fp whh_c = (fp)d_in[4];
  fp bih_c = (fp)d_in[5];
  fp bhh_c = (fp)d_in[6];
  fp wih_p = (fp)d_in[7];
  fp whh_p = (fp)d_in[8];
  fp bih_p = (fp)d_in[9];
  fp bhh_p = (fp)d_in[10];
  fp w_query = (fp)d_in[11];
  fp b_query = (fp)d_in[12];
  fp w_bip = (fp)d_in[13];
  fp b_bip = (fp)d_in[14];
  fp w_masklin = (fp)d_in[15];
  fp ddi = (fp)d_in[16];
  fp embed_fp = (fp)d_in[17];
  const int* fingerprints = (const int*)d_in[18];
  fp adj = (fp)d_in[19];
  const int* seg = (const int*)d_in[20];
  fp w_g0 = (fp)d_in[21];
  fp b_g0 = (fp)d_in[22];
  fp w_g1 = (fp)d_in[23];
  fp b_g1 = (fp)d_in[24];
  fp avg = (fp)d_in[25];
  fp w_out = (fp)d_in[26];
  fp b_out = (fp)d_in[27];
  fp gamma = (fp)d_in[28];
  fp beta = (fp)d_in[29];
  float* out = (float*)d_out;

  char* w = (char*)d_ws;
  size_t off = 0;
  auto alloc = [&](size_t bytes) -> void* {
    void* p = w + off;
    off = (off + bytes + 255) & ~(size_t)255;
    return p;
  };

  float* xp   = (float*)alloc((size_t)2 * 8192 * 768 * 4);    // 50.3 MB
  __half* xhi = (__half*)alloc((size_t)2 * 8192 * 128 * 2);   // 4.2 MB
  __half* xlo = (__half*)alloc((size_t)2 * 8192 * 128 * 2);   // 4.2 MB
  __half* whi = (__half*)alloc((size_t)2 * 768 * 128 * 2);    // 0.4 MB
  __half* wlo = (__half*)alloc((size_t)2 * 768 * 128 * 2);    // 0.4 MB
  uint4* wQ   = (uint4*)alloc((size_t)2 * 32 * 768 * 16);     // 786 KB
  float* mol  = (float*)alloc((size_t)NMOL_N * HH * 4);
  float* embT = (float*)alloc((size_t)HH * LBL * 4);
  float* hcat = (float*)alloc((size_t)BB * 2 * HH * 4);
  float* query = (float*)alloc((size_t)BB * HH * 4);
  float* mw   = (float*)alloc((size_t)NSUBS * LBL * 4);
  int* idxv   = (int*)alloc(256 * 4);
  int* mstart = (int*)alloc((NMOL_N + 1) * 4);

  prep_kernel<<<1190, 256, 0, stream>>>(mask, idxv, seg, mstart, w_masklin,
                                        ddi, mw, whh_c, whh_p, wQ,
                                        x_c, x_p, xhi, xlo,
                                        wih_c, wih_p, whi, wlo);

  xp_mfma<<<dim3(64, 8, 2), 512, 0, stream>>>(xhi, xlo, whi, wlo,
                                              bih_c, bih_p, xp);

  mpnn_mol<<<NMOL_N, 256, 0, stream>>>(fingerprints, embed_fp, adj, mstart,
                                       w_g0, b_g0, w_g1, b_g1, mol);
  mpnn_emb_k<<<LBL, 256, 0, stream>>>(avg, mol, embT);

  gru_dot4<<<256, 1024, 0, stream>>>(xp, wQ, bhh_c, bhh_p, hcat, idxv);

  gemm_f32<<<256, 256, 0, stream>>>(hcat, w_query, b_query, query, BB, HH, 2 * HH);
  tail_fused<<<BB, 256, 0, stream>>>(query, embT, w_out, b_out, gamma, beta,
                                     w_bip, b_bip, mw, out);
}

// Round 17
// 642.096 us; speedup vs baseline: 1.4474x; 1.0213x over previous
//
#include <hip/hip_runtime.h>
#include <hip/hip_bf16.h>
#include <hip/hip_fp16.h>

#define BB 256
#define SS 32
#define II 128
#define HH 256
#define LBL 200
#define NSUBS 491
#define NATOMS_N 8000
#define NMOL_N 600

typedef const float* fp;
typedef __attribute__((ext_vector_type(2))) _Float16 h2t;
typedef __attribute__((ext_vector_type(8))) _Float16 f16x8;
typedef __attribute__((ext_vector_type(4))) float f32x4;

__device__ __forceinline__ float sigm(float x) { return 1.f / (1.f + expf(-x)); }
__device__ __forceinline__ float hlo(unsigned u) {
  return __half2float(__ushort_as_half((unsigned short)(u & 0xffffu)));
}
__device__ __forceinline__ float hhi(unsigned u) {
  return __half2float(__ushort_as_half((unsigned short)(u >> 16)));
}

#if __has_builtin(__builtin_amdgcn_fdot2)
__device__ __forceinline__ float dot2u(unsigned ha, unsigned wa, float acc) {
  return __builtin_amdgcn_fdot2(__builtin_bit_cast(h2t, ha),
                                __builtin_bit_cast(h2t, wa), acc, false);
}
#else
__device__ __forceinline__ float dot2u(unsigned ha, unsigned wa, float acc) {
  acc = fmaf(hlo(ha), hlo(wa), acc);
  return fmaf(hhi(ha), hhi(wa), acc);
}
#endif

// ---------------------------------------------------------------------------
// prep (1190 blocks): idxv, mstart, masked w_masklin, fp16 uint4-packed GRU
// weights wQ (for gru_dot4), and SPLIT-fp16 conversions of x and w_ih.
// ---------------------------------------------------------------------------
__global__ __launch_bounds__(256) void prep_kernel(
    const int* __restrict__ mask, int* __restrict__ idxv,
    const int* __restrict__ seg, int* __restrict__ mstart,
    fp w_masklin, fp ddi, float* __restrict__ mw,
    fp whh_c, fp whh_p, uint4* __restrict__ wQ,
    fp x_c, fp x_p, __half* __restrict__ xhi, __half* __restrict__ xlo,
    fp wih_c, fp wih_p, __half* __restrict__ whi, __half* __restrict__ wlo)
{
  int bx = blockIdx.x, tid = threadIdx.x;
  if (bx == 0) {                         // idx[b] = clamp(sum(mask[b,:]) - 1)
    int s = 0;
    const int* mrow = mask + tid * SS;
    for (int t = 0; t < SS; ++t) s += mrow[t];
    s -= 1;
    if (s < 0) s = 0;
    if (s > SS - 1) s = SS - 1;
    idxv[tid] = s;
  } else if (bx == 1) {                  // mstart[m] = lower_bound(seg, m)
    for (int m = tid; m <= NMOL_N; m += 256) {
      if (m == NMOL_N) { mstart[m] = NATOMS_N; continue; }
      int lo = 0, hi = NATOMS_N;
      while (lo < hi) {
        int mid = (lo + hi) >> 1;
        if (seg[mid] < m) lo = mid + 1; else hi = mid;
      }
      mstart[m] = lo;
    }
  } else if (bx < 6) {                   // mw[s][l] = w_masklin[s][l]*ddi[l][s]
    for (int o = (bx - 2) * 256 + tid; o < NSUBS * LBL; o += 4 * 256) {
      int s = o / LBL, l = o - s * LBL;
      mw[o] = w_masklin[o] * ddi[l * NSUBS + s];
    }
  } else if (bx < 70) {                  // weight pack: one (g, kk8) per block
    int lin = bx - 6;                    // 0..63
    int g = lin >> 5;
    int kk8 = lin & 31;
    fp whh = g ? whh_p : whh_c;
    uint4* dst = wQ + (size_t)(g * 32 + kk8) * 768;
#pragma unroll
    for (int gate = 0; gate < 3; ++gate) {
      const float* src = whh + (size_t)(gate * 256 + tid) * HH + kk8 * 8;
      unsigned v0 = __half_as_ushort(__float2half(src[0]));
      unsigned v1 = __half_as_ushort(__float2half(src[1]));
      unsigned v2 = __half_as_ushort(__float2half(src[2]));
      unsigned v3 = __half_as_ushort(__float2half(src[3]));
      unsigned v4 = __half_as_ushort(__float2half(src[4]));
      unsigned v5 = __half_as_ushort(__float2half(src[5]));
      unsigned v6 = __half_as_ushort(__float2half(src[6]));
      unsigned v7 = __half_as_ushort(__float2half(src[7]));
      uint4 u;
      u.x = v0 | (v1 << 16);
      u.y = v2 | (v3 << 16);
      u.z = v4 | (v5 << 16);
      u.w = v6 | (v7 << 16);
      dst[gate * 256 + tid] = u;
    }
  } else if (bx < 1094) {                // x -> fp16 hi+lo (2 x 1048576)
    int base = (bx - 70) * 2048;
    for (int o = base + tid; o < base + 2048; o += 256) {
      float v = (o < 1048576) ? x_c[o] : x_p[o - 1048576];
      __half h = __float2half(v);
      xhi[o] = h;
      xlo[o] = __float2half(v - __half2float(h));
    }
  } else {                               // w_ih -> fp16 hi+lo (2 x 98304)
    int base = (bx - 1094) * 2048;
    for (int o = base + tid; o < base + 2048; o += 256) {
      float v = (o < 98304) ? wih_c[o] : wih_p[o - 98304];
      __half h = __float2half(v);
      whi[o] = h;
      wlo[o] = __float2half(v - __half2float(h));
    }
  }
}

// ---------------------------------------------------------------------------
// xp v2: LDS-tiled split-fp16 MFMA (verified r12). grid (64, 8, 2) x 512.
// ---------------------------------------------------------------------------
__global__ __launch_bounds__(512) void xp_mfma(
    const __half* __restrict__ xhi, const __half* __restrict__ xlo,
    const __half* __restrict__ whi, const __half* __restrict__ wlo,
    fp bih_c, fp bih_p, float* __restrict__ xp)
{
  int g = blockIdx.z;
  int m0 = blockIdx.x * 128;
  int n0 = blockIdx.y * 96;
  const _Float16* xh = (const _Float16*)xhi + (size_t)g * 8192 * II;
  const _Float16* xl = (const _Float16*)xlo + (size_t)g * 8192 * II;
  const _Float16* wh = (const _Float16*)whi + (size_t)g * 768 * II;
  const _Float16* wl = (const _Float16*)wlo + (size_t)g * 768 * II;
  fp bih = g ? bih_p : bih_c;
  float* xpo = xp + (size_t)g * 8192 * 768;

  __shared__ _Float16 Ah[128][136];
  __shared__ _Float16 Al[128][136];
  __shared__ _Float16 Bh[96][136];
  __shared__ _Float16 Bl[96][136];

  int tid = threadIdx.x;
  for (int i = tid; i < 2048; i += 512) {
    int r = i >> 4, s = i & 15;
    size_t go = (size_t)(m0 + r) * II + s * 8;
    *(f16x8*)&Ah[r][s * 8] = *(const f16x8*)(xh + go);
    *(f16x8*)&Al[r][s * 8] = *(const f16x8*)(xl + go);
  }
  for (int i = tid; i < 1536; i += 512) {
    int r = i >> 4, s = i & 15;
    size_t go = (size_t)(n0 + r) * II + s * 8;
    *(f16x8*)&Bh[r][s * 8] = *(const f16x8*)(wh + go);
    *(f16x8*)&Bl[r][s * 8] = *(const f16x8*)(wl + go);
  }
  __syncthreads();

  int wv = tid >> 6, l = tid & 63;
  int lm = l & 15, q = l >> 4;
  int mr = wv * 16 + lm;

  f16x8 ah0 = *(const f16x8*)&Ah[mr][0 * 32 + q * 8];
  f16x8 ah1 = *(const f16x8*)&Ah[mr][1 * 32 + q * 8];
  f16x8 ah2 = *(const f16x8*)&Ah[mr][2 * 32 + q * 8];
  f16x8 ah3 = *(const f16x8*)&Ah[mr][3 * 32 + q * 8];
  f16x8 al0 = *(const f16x8*)&Al[mr][0 * 32 + q * 8];
  f16x8 al1 = *(const f16x8*)&Al[mr][1 * 32 + q * 8];
  f16x8 al2 = *(const f16x8*)&Al[mr][2 * 32 + q * 8];
  f16x8 al3 = *(const f16x8*)&Al[mr][3 * 32 + q * 8];

#pragma unroll
  for (int nj = 0; nj < 6; ++nj) {
    int nr = nj * 16 + lm;
    f32x4 acc = {0.f, 0.f, 0.f, 0.f};
    {
      f16x8 b = *(const f16x8*)&Bh[nr][0 * 32 + q * 8];
      f16x8 c = *(const f16x8*)&Bl[nr][0 * 32 + q * 8];
      acc = __builtin_amdgcn_mfma_f32_16x16x32_f16(ah0, b, acc, 0, 0, 0);
      acc = __builtin_amdgcn_mfma_f32_16x16x32_f16(al0, b, acc, 0, 0, 0);
      acc = __builtin_amdgcn_mfma_f32_16x16x32_f16(ah0, c, acc, 0, 0, 0);
    }
    {
      f16x8 b = *(const f16x8*)&Bh[nr][1 * 32 + q * 8];
      f16x8 c = *(const f16x8*)&Bl[nr][1 * 32 + q * 8];
      acc = __builtin_amdgcn_mfma_f32_16x16x32_f16(ah1, b, acc, 0, 0, 0);
      acc = __builtin_amdgcn_mfma_f32_16x16x32_f16(al1, b, acc, 0, 0, 0);
      acc = __builtin_amdgcn_mfma_f32_16x16x32_f16(ah1, c, acc, 0, 0, 0);
    }
    {
      f16x8 b = *(const f16x8*)&Bh[nr][2 * 32 + q * 8];
      f16x8 c = *(const f16x8*)&Bl[nr][2 * 32 + q * 8];
      acc = __builtin_amdgcn_mfma_f32_16x16x32_f16(ah2, b, acc, 0, 0, 0);
      acc = __builtin_amdgcn_mfma_f32_16x16x32_f16(al2, b, acc, 0, 0, 0);
      acc = __builtin_amdgcn_mfma_f32_16x16x32_f16(ah2, c, acc, 0, 0, 0);
    }
    {
      f16x8 b = *(const f16x8*)&Bh[nr][3 * 32 + q * 8];
      f16x8 c = *(const f16x8*)&Bl[nr][3 * 32 + q * 8];
      acc = __builtin_amdgcn_mfma_f32_16x16x32_f16(ah3, b, acc, 0, 0, 0);
      acc = __builtin_amdgcn_mfma_f32_16x16x32_f16(al3, b, acc, 0, 0, 0);
      acc = __builtin_amdgcn_mfma_f32_16x16x32_f16(ah3, c, acc, 0, 0, 0);
    }
    float bias = bih[n0 + nr];
#pragma unroll
    for (int r = 0; r < 4; ++r)
      xpo[(size_t)(m0 + wv * 16 + q * 4 + r) * 768 + n0 + nr] = acc[r] + bias;
  }
}

// ---------------------------------------------------------------------------
// fully-fused MPNN: one block per molecule. 8-wide k-unroll (r14, verified).
// ---------------------------------------------------------------------------
__global__ __launch_bounds__(256) void mpnn_mol(
    const int* __restrict__ fingerprints, fp embed_fp, fp adj,
    const int* __restrict__ mstart, fp w_g0, fp b_g0, fp w_g1, fp b_g1,
    float* __restrict__ mol)
{
  int m = blockIdx.x, tid = threadIdx.x;
  int a0 = mstart[m], a1 = mstart[m + 1];
  int sz = a1 - a0;
  if (sz < 0) sz = 0;
  if (sz > 14) sz = 14;

  __shared__ float v[14][260];
  __shared__ float adjb[14][16];

#pragma unroll
  for (int i = 0; i < 14; ++i) {
    float val = 0.f;
    if (i < sz) {
      int f = fingerprints[a0 + i] & 1023;
      val = embed_fp[(size_t)f * HH + tid];
    }
    v[i][tid] = val;
  }
  if (tid < 224) {
    int i = tid >> 4, jj = tid & 15;
    float a = 0.f;
    if (i < sz && jj < sz)
      a = adj[(size_t)(a0 + i) * NATOMS_N + a0 + jj];
    adjb[i][jj] = a;
  }
  __syncthreads();

  float acc[14];
  for (int rd = 0; rd < 2; ++rd) {
    const float* wp0 = (rd ? w_g1 : w_g0) + tid;
#pragma unroll
    for (int i = 0; i < 14; ++i) acc[i] = 0.f;
    for (int k = 0; k < HH; k += 8) {
      float w0 = wp0[(size_t)k * HH];
      float w1 = wp0[(size_t)(k + 1) * HH];
      float w2 = wp0[(size_t)(k + 2) * HH];
      float w3 = wp0[(size_t)(k + 3) * HH];
      float w4 = wp0[(size_t)(k + 4) * HH];
      float w5 = wp0[(size_t)(k + 5) * HH];
      float w6 = wp0[(size_t)(k + 6) * HH];
      float w7 = wp0[(size_t)(k + 7) * HH];
#pragma unroll
      for (int i = 0; i < 14; ++i) {
        float4 va = *(const float4*)&v[i][k];
        float4 vb = *(const float4*)&v[i][k + 4];
        acc[i] = fmaf(va.x, w0, acc[i]);
        acc[i] = fmaf(va.y, w1, acc[i]);
        acc[i] = fmaf(va.z, w2, acc[i]);
        acc[i] = fmaf(va.w, w3, acc[i]);
        acc[i] = fmaf(vb.x, w4, acc[i]);
        acc[i] = fmaf(vb.y, w5, acc[i]);
        acc[i] = fmaf(vb.z, w6, acc[i]);
        acc[i] = fmaf(vb.w, w7, acc[i]);
      }
    }
    float bias = (rd ? b_g1 : b_g0)[tid];
    float hreg[14];
#pragma unroll
    for (int i = 0; i < 14; ++i) hreg[i] = fmaxf(acc[i] + bias, 0.f);
#pragma unroll
    for (int i = 0; i < 14; ++i) {
      float s = hreg[i];
#pragma unroll
      for (int jj = 0; jj < 14; ++jj) s = fmaf(adjb[i][jj], hreg[jj], s);
      acc[i] = s;
    }
    if (rd == 0) {
      __syncthreads();
#pragma unroll
      for (int i = 0; i < 14; ++i) v[i][tid] = acc[i];
      __syncthreads();
    }
  }
  float msum = 0.f;
#pragma unroll
  for (int i = 0; i < 14; ++i) if (i < sz) msum += acc[i];
  mol[(size_t)m * HH + tid] = msum;
}

// ---------------------------------------------------------------------------
// mpnn_emb^T[h][d] = sum_m avg[d][m]*mol[m][h]. 8 independent chains.
// ---------------------------------------------------------------------------
__global__ __launch_bounds__(256) void mpnn_emb_k(
    fp avg, const float* __restrict__ mol, float* __restrict__ embT)
{
  int d = blockIdx.x, tid = threadIdx.x;
  const float* ar = avg + (size_t)d * NMOL_N;
  float a0 = 0.f, a1 = 0.f, a2 = 0.f, a3 = 0.f;
  float a4 = 0.f, a5 = 0.f, a6 = 0.f, a7 = 0.f;
  for (int m = 0; m < NMOL_N; m += 8) {
    a0 = fmaf(ar[m],     mol[(size_t)m * HH + tid],       a0);
    a1 = fmaf(ar[m + 1], mol[(size_t)(m + 1) * HH + tid], a1);
    a2 = fmaf(ar[m + 2], mol[(size_t)(m + 2) * HH + tid], a2);
    a3 = fmaf(ar[m + 3], mol[(size_t)(m + 3) * HH + tid], a3);
    a4 = fmaf(ar[m + 4], mol[(size_t)(m + 4) * HH + tid], a4);
    a5 = fmaf(ar[m + 5], mol[(size_t)(m + 5) * HH + tid], a5);
    a6 = fmaf(ar[m + 6], mol[(size_t)(m + 6) * HH + tid], a6);
    a7 = fmaf(ar[m + 7], mol[(size_t)(m + 7) * HH + tid], a7);
  }
  embT[(size_t)tid * LBL + d] =
      ((a0 + a1) + (a2 + a3)) + ((a4 + a5) + (a6 + a7));
}

// ---------------------------------------------------------------------------
// GRU v7.2: the r16 failure was a UNIT BUG, now fixed: v7 indexed hsh in
// u32 units (kq*32 u32 = 64 halfs); v7.1 changed hsh to _Float16[] but kept
// kq*32 -> each k-quarter read the wrong 64-half window (k 160..255 never
// read, k 32..127 double-counted) -> absmax 1.1. Fix: kq*64 in half units.
// Structure otherwise identical to v7.1: 2 barriers/step, h in register,
// direct 2-byte DS store of the fp16 mirror (distinct addr per thread).
// ---------------------------------------------------------------------------
__global__ __launch_bounds__(1024) void gru_dot4(
    fp xp, const uint4* __restrict__ wQ, fp bhh_c, fp bhh_p,
    float* __restrict__ hcat, const int* __restrict__ idxv)
{
  int blk = blockIdx.x;
  int g = blk >> 7;
  int pair = blk & 127;
  int b1 = pair * 2, b2 = b1 + 1;
  int tid = threadIdx.x;
  int j = tid & 255;
  int kq = tid >> 8;                   // k-quarter 0..3

  __shared__ _Float16 hsh[2][272];     // fp16 h mirror, padded rows (16B-align)
  __shared__ float red[24][260];       // [kq*6 + batch*3 + gate][j]

  const uint4* wg = wQ + (size_t)(g * 32 + kq * 8) * 768 + j;
  fp bhh = g ? bhh_p : bhh_c;
  const float* xpg = xp + (size_t)g * 8192 * 768;

  if (tid < 272) ((unsigned*)hsh)[tid] = 0u;   // 2*272 halfs = 272 dwords
  float br = bhh[j], bz = bhh[j + 256], bn = bhh[j + 512];
  int bidx = kq & 1;                   // gate-phase batch (threads < 512)
  int myb = bidx ? b2 : b1;
  int myid = idxv[myb];
  float hreg = 0.f;                    // per-thread h state (gate threads)
  __syncthreads();

  for (int t = 0; t < SS; ++t) {
    // dot phase: packed fp16 h (uint4 = 8 halfs) x packed fp16 weights.
    // Base = kq*64 HALF units (the r16 bug was kq*32 here).
    const uint4* h1p = (const uint4*)&hsh[0][kq * 64];
    const uint4* h2p = (const uint4*)&hsh[1][kq * 64];
    float s1r = 0.f, s1z = 0.f, s1n = 0.f;
    float s2r = 0.f, s2z = 0.f, s2n = 0.f;
#pragma unroll
    for (int i = 0; i < 8; ++i) {
      uint4 H1 = h1p[i];
      uint4 H2 = h2p[i];
      const uint4* base = wg + (size_t)i * 768;
      uint4 ur = base[0];
      uint4 uz = base[256];
      uint4 un = base[512];
      s1r = dot2u(H1.x, ur.x, s1r); s1r = dot2u(H1.y, ur.y, s1r);
      s1r = dot2u(H1.z, ur.z, s1r); s1r = dot2u(H1.w, ur.w, s1r);
      s1z = dot2u(H1.x, uz.x, s1z); s1z = dot2u(H1.y, uz.y, s1z);
      s1z = dot2u(H1.z, uz.z, s1z); s1z = dot2u(H1.w, uz.w, s1z);
      s1n = dot2u(H1.x, un.x, s1n); s1n = dot2u(H1.y, un.y, s1n);
      s1n = dot2u(H1.z, un.z, s1n); s1n = dot2u(H1.w, un.w, s1n);
      s2r = dot2u(H2.x, ur.x, s2r); s2r = dot2u(H2.y, ur.y, s2r);
      s2r = dot2u(H2.z, ur.z, s2r); s2r = dot2u(H2.w, ur.w, s2r);
      s2z = dot2u(H2.x, uz.x, s2z); s2z = dot2u(H2.y, uz.y, s2z);
      s2z = dot2u(H2.z, uz.z, s2z); s2z = dot2u(H2.w, uz.w, s2z);
      s2n = dot2u(H2.x, un.x, s2n); s2n = dot2u(H2.y, un.y, s2n);
      s2n = dot2u(H2.z, un.z, s2n); s2n = dot2u(H2.w, un.w, s2n);
    }
    int rb = kq * 6;
    red[rb + 0][j] = s1r; red[rb + 1][j] = s1z; red[rb + 2][j] = s1n;
    red[rb + 3][j] = s2r; red[rb + 4][j] = s2z; red[rb + 5][j] = s2n;
    __syncthreads();        // partials visible; all hsh reads of step t done

    // gate phase: threads < 512, (bidx, j); h state in register; writes
    // the fp16 mirror directly (2-byte DS store, distinct addr per thread)
    if (tid < 512) {
      int bb = bidx * 3;
      float sr = red[bb + 0][j] + red[bb + 6][j] + red[bb + 12][j] + red[bb + 18][j];
      float sz = red[bb + 1][j] + red[bb + 7][j] + red[bb + 13][j] + red[bb + 19][j];
      float sn = red[bb + 2][j] + red[bb + 8][j] + red[bb + 14][j] + red[bb + 20][j];
      const float* xrow = xpg + ((size_t)myb * SS + t) * 768;
      float r = sigm(xrow[j] + sr + br);
      float z = sigm(xrow[j + 256] + sz + bz);
      float n = tanhf(xrow[j + 512] + r * (sn + bn));
      float hnew = (1.f - z) * n + z * hreg;
      hreg = hnew;
      hsh[bidx][j] = (_Float16)hnew;
      if (t == myid) hcat[(size_t)myb * 512 + g * 256 + j] = fmaxf(hnew, 0.f);
    }
    __syncthreads();        // hsh update visible before next dot phase
  }
}

// ---------------------------------------------------------------------------
// fp32 GEMM for query: 4 independent acc chains (r14, verified).
// ---------------------------------------------------------------------------
__global__ __launch_bounds__(256) void gemm_f32(
    const float* __restrict__ A, fp W, fp bias, float* __restrict__ C,
    int M, int N, int K)
{
  int ntiles = N >> 4;
  int mt = blockIdx.x / ntiles, nt = blockIdx.x - mt * ntiles;
  int m0 = mt << 4, n0 = nt << 4;
  int tid = threadIdx.x;
  int ni = tid & 15, mi = tid >> 4;
  __shared__ float As[16][68];
  float a0 = 0.f, a1 = 0.f, a2 = 0.f, a3 = 0.f;
  for (int k0 = 0; k0 < K; k0 += 64) {
    __syncthreads();
    for (int i = tid; i < 1024; i += 256) {
      int r = i >> 6, kk = i & 63;
      As[r][kk] = A[(size_t)(m0 + r) * K + k0 + kk];
    }
    __syncthreads();
    const float* wp = W + (size_t)k0 * N + n0 + ni;
#pragma unroll 4
    for (int kk = 0; kk < 64; kk += 4) {
      a0 = fmaf(As[mi][kk],     wp[(size_t)kk * N],       a0);
      a1 = fmaf(As[mi][kk + 1], wp[(size_t)(kk + 1) * N], a1);
      a2 = fmaf(As[mi][kk + 2], wp[(size_t)(kk + 2) * N], a2);
      a3 = fmaf(As[mi][kk + 3], wp[(size_t)(kk + 3) * N], a3);
    }
  }
  float acc = (a0 + a1) + (a2 + a3) + bias[n0 + ni];
  C[(size_t)(m0 + mi) * N + n0 + ni] = acc;
}

// ---------------------------------------------------------------------------
// fused tail: 4 independent acc chains per loop (r14, verified).
// ---------------------------------------------------------------------------
__global__ __launch_bounds__(256) void tail_fused(
    const float* __restrict__ query, const float* __restrict__ embT,
    fp w_out, fp b_out, fp gamma, fp beta,
    fp w_bip, fp b_bip, const float* __restrict__ mw,
    float* __restrict__ out)
{
  int b = blockIdx.x, tid = threadIdx.x;
  __shared__ float q[HH];
  __shared__ float mrow[LBL];
  __shared__ float bips[NSUBS];
  __shared__ float red[256];
  q[tid] = query[(size_t)b * HH + tid];
  __syncthreads();
  if (tid < LBL) {
    float t0 = 0.f, t1 = 0.f, t2 = 0.f, t3 = 0.f;
    for (int k = 0; k < HH; k += 4) {
      t0 = fmaf(q[k],     embT[(size_t)k * LBL + tid],       t0);
      t1 = fmaf(q[k + 1], embT[(size_t)(k + 1) * LBL + tid], t1);
      t2 = fmaf(q[k + 2], embT[(size_t)(k + 2) * LBL + tid], t2);
      t3 = fmaf(q[k + 3], embT[(size_t)(k + 3) * LBL + tid], t3);
    }
    mrow[tid] = sigm((t0 + t1) + (t2 + t3));
  }
  for (int s = tid; s < NSUBS; s += 256) {
    float t0 = b_bip[s], t1 = 0.f, t2 = 0.f, t3 = 0.f;
    for (int k = 0; k < HH; k += 4) {
      t0 = fmaf(q[k],     w_bip[(size_t)k * NSUBS + s],       t0);
      t1 = fmaf(q[k + 1], w_bip[(size_t)(k + 1) * NSUBS + s], t1);
      t2 = fmaf(q[k + 2], w_bip[(size_t)(k + 2) * NSUBS + s], t2);
      t3 = fmaf(q[k + 3], w_bip[(size_t)(k + 3) * NSUBS + s], t3);
    }
    bips[s] = (t0 + t1) + (t2 + t3);
  }
  __syncthreads();
  float x2 = 0.f;
  if (tid < LBL) {
    float t0 = b_out[tid] + mrow[tid], t1 = 0.f, t2 = 0.f, t3 = 0.f;
    for (int jj = 0; jj < LBL; jj += 4) {
      t0 = fmaf(mrow[jj],     w_out[(jj) * LBL + tid],     t0);
      t1 = fmaf(mrow[jj + 1], w_out[(jj + 1) * LBL + tid], t1);
      t2 = fmaf(mrow[jj + 2], w_out[(jj + 2) * LBL + tid], t2);
      t3 = fmaf(mrow[jj + 3], w_out[(jj + 3) * LBL + tid], t3);
    }
    x2 = (t0 + t1) + (t2 + t3);
  }
  red[tid] = (tid < LBL) ? x2 : 0.f;
  __syncthreads();
  for (int s = 128; s > 0; s >>= 1) {
    if (tid < s) red[tid] += red[tid + s];
    __syncthreads();
  }
  float mu = red[0] / (float)LBL;
  __syncthreads();
  float dv = (tid < LBL) ? (x2 - mu) : 0.f;
  red[tid] = dv * dv;
  __syncthreads();
  for (int s = 128; s > 0; s >>= 1) {
    if (tid < s) red[tid] += red[tid + s];
    __syncthreads();
  }
  float var = red[0] / (float)LBL;
  if (tid < LBL) {
    float matt = (x2 - mu) * rsqrtf(var + 1e-5f) * gamma[tid] + beta[tid];
    float t0 = 0.f, t1 = 0.f, t2 = 0.f, t3 = 0.f;
    int s = 0;
    for (; s + 3 < NSUBS; s += 4) {
      t0 = fmaf(bips[s],     mw[(size_t)s * LBL + tid],       t0);
      t1 = fmaf(bips[s + 1], mw[(size_t)(s + 1) * LBL + tid], t1);
      t2 = fmaf(bips[s + 2], mw[(size_t)(s + 2) * LBL + tid], t2);
      t3 = fmaf(bips[s + 3], mw[(size_t)(s + 3) * LBL + tid], t3);
    }
    for (; s < NSUBS; ++s) t0 = fmaf(bips[s], mw[(size_t)s * LBL + tid], t0);
    out[(size_t)b * LBL + tid] = ((t0 + t1) + (t2 + t3)) * matt;
  }
}

// ---------------------------------------------------------------------------
extern "C" void kernel_launch(void* const* d_in, const int* in_sizes, int n_in,
                              void* d_out, int out_size, void* d_ws, size_t ws_size,
                              hipStream_t stream)
{
  fp x_c   = (fp)d_in[0];
  fp x_p   = (fp)d_in[1];
  const int* mask = (const int*)d_in[2];
  fp wih_c = (fp)d_in[3];
  fp whh_c = (fp)d_in[4];
  fp bih_c = (fp)d_in[5];
  fp bhh_c = (fp)d_in[6];
  fp wih_p = (fp)d_in[7];
  fp whh_p = (fp)d_in[8];
  fp bih_p = (fp)d_in[9];
  fp bhh_p = (fp)d_in[10];
  fp w_query = (fp)d_in[11];
  fp b_query = (fp)d_in[12];
  fp w_bip = (fp)d_in[13];
  fp b_bip = (fp)d_in[14];
  fp w_masklin = (fp)d_in[15];
  fp ddi = (fp)d_in[16];
  fp embed_fp = (fp)d_in[17];
  const int* fingerprints = (const int*)d_in[18];
  fp adj = (fp)d_in[19];
  const int* seg = (const int*)d_in[20];
  fp w_g0 = (fp)d_in[21];
  fp b_g0 = (fp)d_in[22];
  fp w_g1 = (fp)d_in[23];
  fp b_g1 = (fp)d_in[24];
  fp avg = (fp)d_in[25];
  fp w_out = (fp)d_in[26];
  fp b_out = (fp)d_in[27];
  fp gamma = (fp)d_in[28];
  fp beta = (fp)d_in[29];
  float* out = (float*)d_out;

  char* w = (char*)d_ws;
  size_t off = 0;
  auto alloc = [&](size_t bytes) -> void* {
    void* p = w + off;
    off = (off + bytes + 255) & ~(size_t)255;
    return p;
  };

  float* xp   = (float*)alloc((size_t)2 * 8192 * 768 * 4);    // 50.3 MB
  __half* xhi = (__half*)alloc((size_t)2 * 8192 * 128 * 2);   // 4.2 MB
  __half* xlo = (__half*)alloc((size_t)2 * 8192 * 128 * 2);   // 4.2 MB
  __half* whi = (__half*)alloc((size_t)2 * 768 * 128 * 2);    // 0.4 MB
  __half* wlo = (__half*)alloc((size_t)2 * 768 * 128 * 2);    // 0.4 MB
  uint4* wQ   = (uint4*)alloc((size_t)2 * 32 * 768 * 16);     // 786 KB
  float* mol  = (float*)alloc((size_t)NMOL_N * HH * 4);
  float* embT = (float*)alloc((size_t)HH * LBL * 4);
  float* hcat = (float*)alloc((size_t)BB * 2 * HH * 4);
  float* query = (float*)alloc((size_t)BB * HH * 4);
  float* mw   = (float*)alloc((size_t)NSUBS * LBL * 4);
  int* idxv   = (int*)alloc(256 * 4);
  int* mstart = (int*)alloc((NMOL_N + 1) * 4);

  prep_kernel<<<1190, 256, 0, stream>>>(mask, idxv, seg, mstart, w_masklin,
                                        ddi, mw, whh_c, whh_p, wQ,
                                        x_c, x_p, xhi, xlo,
                                        wih_c, wih_p, whi, wlo);

  xp_mfma<<<dim3(64, 8, 2), 512, 0, stream>>>(xhi, xlo, whi, wlo,
                                              bih_c, bih_p, xp);

  mpnn_mol<<<NMOL_N, 256, 0, stream>>>(fingerprints, embed_fp, adj, mstart,
                                       w_g0, b_g0, w_g1, b_g1, mol);
  mpnn_emb_k<<<LBL, 256, 0, stream>>>(avg, mol, embT);

  gru_dot4<<<256, 1024, 0, stream>>>(xp, wQ, bhh_c, bhh_p, hcat, idxv);

  gemm_f32<<<256, 256, 0, stream>>>(hcat, w_query, b_query, query, BB, HH, 2 * HH);
  tail_fused<<<BB, 256, 0, stream>>>(query, embT, w_out, b_out, gamma, beta,
                                     w_bip, b_bip, mw, out);
}